// Round 7
// baseline (717.532 us; speedup 1.0000x reference)
//
#include <hip/hip_runtime.h>
#include <hip/hip_bf16.h>

#define NN 100000
#define NE 800000
#define SCAN_NB 98   // ceil(NN / 1024)

typedef __attribute__((ext_vector_type(8))) short bf16x8;
typedef __attribute__((ext_vector_type(4))) float f32x4;

__device__ __forceinline__ short f2b(float f) {
    unsigned u = __float_as_uint(f);
    unsigned r = (u + 0x7fffu + ((u >> 16) & 1u)) >> 16;
    return (short)r;
}
__device__ __forceinline__ float b2f(short s) {
    return __uint_as_float(((unsigned)(unsigned short)s) << 16);
}
// packed RNE f32x2 -> bf16x2 (lo=a, hi=b); bit-identical to f2b
__device__ __forceinline__ unsigned cvt2(float a, float b) {
    unsigned r;
    asm("v_cvt_pk_bf16_f32 %0, %1, %2" : "=v"(r) : "v"(a), "v"(b));
    return r;
}
__device__ __forceinline__ float blo(unsigned u) { return __uint_as_float(u << 16); }
__device__ __forceinline__ float bhi(unsigned u) { return __uint_as_float(u & 0xffff0000u); }

// ---------------- fused: weight prep (blocks 0..4) + degree histogram (blocks 5..) ----------------
__global__ __launch_bounds__(256) void k_prep_hist(
    const float* __restrict__ We, const float* __restrict__ Wm1,
    const float* __restrict__ W2l, const float* __restrict__ W2r,
    short* __restrict__ WteT, short* __restrict__ WmsT,
    short* __restrict__ WmdT, short* __restrict__ W2cT,
    const int* __restrict__ ei, int* __restrict__ deg)
{
    int b = blockIdx.x;
    int tid = threadIdx.x;
    if (b >= 5) {
        int e = (b - 5) * 256 + tid;
        if (e < NE) atomicAdd(&deg[ei[NE + e]], 1);
        return;
    }
    if (tid >= 128) return;
    int j = tid;
    if (b == 0) {
        for (int k = 0; k < 32; k++)
            WteT[j * 32 + k] = (k < 16) ? f2b(We[k * 128 + j]) : (short)0;
    } else if (b == 1) {
        for (int k = 0; k < 128; k++) WmsT[j * 128 + k] = f2b(Wm1[k * 128 + j]);
    } else if (b == 2) {
        for (int k = 0; k < 128; k++) WmdT[j * 128 + k] = f2b(Wm1[(128 + k) * 128 + j]);
    } else if (b == 3) {
        for (int k = 0; k < 128; k++) W2cT[j * 256 + k] = f2b(W2l[k * 128 + j]);
    } else {
        for (int k = 0; k < 128; k++) W2cT[j * 256 + 128 + k] = f2b(W2r[k * 128 + j]);
    }
}

// phase a: per-block exclusive scan (coalesced), block sums out
__global__ __launch_bounds__(1024) void k_scan_a(const int* __restrict__ deg,
    int* __restrict__ tmp, int* __restrict__ bsum)
{
    __shared__ int sh[1024];
    int t = threadIdx.x, b = blockIdx.x;
    int idx = b * 1024 + t;
    int v = (idx < NN) ? deg[idx] : 0;
    sh[t] = v;
    __syncthreads();
    for (int ofs = 1; ofs < 1024; ofs <<= 1) {
        int u = (t >= ofs) ? sh[t - ofs] : 0;
        __syncthreads();
        sh[t] += u;
        __syncthreads();
    }
    if (idx < NN) tmp[idx] = sh[t] - v;   // exclusive within block
    if (t == 1023) bsum[b] = sh[1023];
}

__global__ void k_scan_b(const int* __restrict__ bsum, int* __restrict__ boff,
    int* __restrict__ rowptr)
{
    if (threadIdx.x == 0) {
        int acc = 0;
        for (int i = 0; i < SCAN_NB; i++) { boff[i] = acc; acc += bsum[i]; }
        rowptr[NN] = acc;
    }
}

__global__ __launch_bounds__(1024) void k_scan_c(const int* __restrict__ tmp,
    const int* __restrict__ boff, int* __restrict__ rowptr, int* __restrict__ wp)
{
    int b = blockIdx.x, t = threadIdx.x;
    int idx = b * 1024 + t;
    if (idx < NN) {
        int v = boff[b] + tmp[idx];
        rowptr[idx] = v; wp[idx] = v;
    }
}

// ---------------- fused: CSR scatter (blocks 0..3124) + edge bne stats (blocks 3125..) ----------------
#define SCAT_NB 3125
__global__ __launch_bounds__(256) void k_scat_e0(
    const int* __restrict__ ei, int* __restrict__ wp, int* __restrict__ elist,
    const float* __restrict__ ea, const short* __restrict__ WteT, const float* __restrict__ be,
    float* __restrict__ ssum, float* __restrict__ ssq)
{
    const int tid = threadIdx.x;
    if (blockIdx.x < SCAT_NB) {
        int e = blockIdx.x * 256 + tid;
        if (e < NE) {
            int d = ei[NE + e];
            int pos = atomicAdd(&wp[d], 1);
            elist[pos] = ei[e];
        }
        return;
    }
    // ---- mode0: bne stats of t = relu(ea@We+be), eattr pipelined ----
    __shared__ float sRed[2][128];
    const int wave = tid >> 6, lane = tid & 63;
    const int quad = lane >> 4, ln = lane & 15;
    const int waveM = wave >> 1, waveN = wave & 1;
    const int colbase = 64 * waveN, row16 = 16 * waveM;
    if (tid < 128) { sRed[0][tid] = 0.f; sRed[1][tid] = 0.f; }

    bf16x8 bWe[4];
    float bec[4];
    #pragma unroll
    for (int nt = 0; nt < 4; nt++) {
        bWe[nt] = *(const bf16x8*)(WteT + (colbase + nt * 16 + ln) * 32 + quad * 8);
        bec[nt] = be[colbase + nt * 16 + ln];
    }
    float s1[4] = {0,0,0,0}, s2[4] = {0,0,0,0};
    f32x4 zero = {0.f, 0.f, 0.f, 0.f};
    __syncthreads();

    const int G = gridDim.x - SCAT_NB;
    const int NT = NE / 32;
    float4 fe0 = {0,0,0,0}, fe1 = {0,0,0,0};
    int t = blockIdx.x - SCAT_NB;
    if (t < NT && quad < 2) {
        const float* p = ea + (size_t)(t * 32 + row16 + ln) * 16 + quad * 8;
        fe0 = *(const float4*)p; fe1 = *(const float4*)(p + 4);
    }
    for (; t < NT; t += G) {
        bf16x8 aE;
        if (quad < 2) {
            uint4 uw;
            uw.x = cvt2(fe0.x, fe0.y); uw.y = cvt2(fe0.z, fe0.w);
            uw.z = cvt2(fe1.x, fe1.y); uw.w = cvt2(fe1.z, fe1.w);
            aE = *(bf16x8*)&uw;
        } else {
            #pragma unroll
            for (int i = 0; i < 8; i++) aE[i] = 0;
        }
        int t1 = t + G;
        if (t1 < NT && quad < 2) {
            const float* p = ea + (size_t)(t1 * 32 + row16 + ln) * 16 + quad * 8;
            fe0 = *(const float4*)p; fe1 = *(const float4*)(p + 4);
        }
        f32x4 tacc[4];
        #pragma unroll
        for (int nt = 0; nt < 4; nt++)
            tacc[nt] = __builtin_amdgcn_mfma_f32_16x16x32_bf16(aE, bWe[nt], zero, 0, 0, 0);
        #pragma unroll
        for (int nt = 0; nt < 4; nt++)
            #pragma unroll
            for (int r = 0; r < 4; r++) {
                float v = fmaxf(tacc[nt][r] + bec[nt], 0.f);
                s1[nt] += v; s2[nt] += v * v;
            }
    }
    #pragma unroll
    for (int nt = 0; nt < 4; nt++) {
        float a1 = s1[nt], a2 = s2[nt];
        a1 += __shfl_down(a1, 32); a1 += __shfl_down(a1, 16);
        a2 += __shfl_down(a2, 32); a2 += __shfl_down(a2, 16);
        if (quad == 0) {
            atomicAdd(&sRed[0][colbase + nt * 16 + ln], a1);
            atomicAdd(&sRed[1][colbase + nt * 16 + ln], a2);
        }
    }
    __syncthreads();
    if (tid < 128) {
        atomicAdd(&ssum[tid], sRed[0][tid]);
        atomicAdd(&ssq[tid],  sRed[1][tid]);
    }
}

// ---------------- fused: gather-mean layer1 (blocks 0..12499) + fold_e (block 12500) ----------------
__global__ __launch_bounds__(256) void k_gagg1f(const float* __restrict__ x,
    const int* __restrict__ rowptr, const int* __restrict__ elist, float* __restrict__ meanX,
    const float* __restrict__ essum, const float* __restrict__ essq,
    const float* __restrict__ bne_g, const float* __restrict__ bne_b,
    const float* __restrict__ Wm1, const float* __restrict__ bm1,
    short* __restrict__ W1pT, float* __restrict__ bm1p)
{
    if (blockIdx.x == NN / 8) {
        __shared__ float sa[128], scc[128];
        int tid = threadIdx.x;
        if (tid < 128) {
            float m = essum[tid] / (float)NE;
            float var = essq[tid] / (float)NE - m * m;
            float rs = rsqrtf(var + 1e-5f);
            float a = bne_g[tid] * rs;
            sa[tid] = a; scc[tid] = bne_b[tid] - m * a;
        }
        __syncthreads();
        if (tid < 128) {
            float acc = bm1[tid];
            for (int k = 0; k < 128; k++) {
                float w = Wm1[(256 + k) * 128 + tid];
                W1pT[tid * 128 + k] = f2b(sa[k] * w);
                acc += scc[k] * w;
            }
            bm1p[tid] = acc;
        }
        return;
    }
    int n = blockIdx.x * 8 + (threadIdx.x >> 5);
    int j = threadIdx.x & 31;
    int b = rowptr[n], e = rowptr[n + 1];
    float acc = 0.f;
    int i = b;
    for (; i + 4 <= e; i += 4) {
        int s0 = elist[i], s1 = elist[i + 1], s2 = elist[i + 2], s3 = elist[i + 3];
        float a0 = x[(size_t)s0 * 32 + j];
        float a1 = x[(size_t)s1 * 32 + j];
        float a2 = x[(size_t)s2 * 32 + j];
        float a3 = x[(size_t)s3 * 32 + j];
        acc += (a0 + a1) + (a2 + a3);
    }
    for (; i < e; i++) acc += x[(size_t)elist[i] * 32 + j];
    float inv = (e > b) ? 1.0f / (float)(e - b) : 1.0f;
    meanX[(size_t)n * 32 + j] = acc * inv;
}

// ---------------- gagg2: gather-mean of bnrelu(h1) (bn1 inlined from stats) ----------------
__global__ __launch_bounds__(256) void k_gagg2(const short* __restrict__ h1b,
    const int* __restrict__ rowptr, const int* __restrict__ elist,
    const float* __restrict__ ssum1, const float* __restrict__ ssq1,
    const float* __restrict__ g1, const float* __restrict__ b1g, short* __restrict__ m2b)
{
    int n = blockIdx.x * 8 + (threadIdx.x >> 5);
    int c0 = (threadIdx.x & 31) * 4;
    float sc[4], sh[4];
    #pragma unroll
    for (int i = 0; i < 4; i++) {
        float m = ssum1[c0 + i] / (float)NN;
        float var = ssq1[c0 + i] / (float)NN - m * m;
        float rs = rsqrtf(var + 1e-5f);
        float s = g1[c0 + i] * rs;
        sc[i] = s; sh[i] = b1g[c0 + i] - m * s;
    }
    int b = rowptr[n], e = rowptr[n + 1];
    float acc[4] = {0.f, 0.f, 0.f, 0.f};
    int i = b;
    for (; i + 4 <= e; i += 4) {
        int s0 = elist[i], s1 = elist[i + 1], s2 = elist[i + 2], s3 = elist[i + 3];
        uint2 u0 = *(const uint2*)(h1b + (size_t)s0 * 128 + c0);
        uint2 u1 = *(const uint2*)(h1b + (size_t)s1 * 128 + c0);
        uint2 u2 = *(const uint2*)(h1b + (size_t)s2 * 128 + c0);
        uint2 u3 = *(const uint2*)(h1b + (size_t)s3 * 128 + c0);
        acc[0] += fmaxf(blo(u0.x) * sc[0] + sh[0], 0.f) + fmaxf(blo(u1.x) * sc[0] + sh[0], 0.f)
                + fmaxf(blo(u2.x) * sc[0] + sh[0], 0.f) + fmaxf(blo(u3.x) * sc[0] + sh[0], 0.f);
        acc[1] += fmaxf(bhi(u0.x) * sc[1] + sh[1], 0.f) + fmaxf(bhi(u1.x) * sc[1] + sh[1], 0.f)
                + fmaxf(bhi(u2.x) * sc[1] + sh[1], 0.f) + fmaxf(bhi(u3.x) * sc[1] + sh[1], 0.f);
        acc[2] += fmaxf(blo(u0.y) * sc[2] + sh[2], 0.f) + fmaxf(blo(u1.y) * sc[2] + sh[2], 0.f)
                + fmaxf(blo(u2.y) * sc[2] + sh[2], 0.f) + fmaxf(blo(u3.y) * sc[2] + sh[2], 0.f);
        acc[3] += fmaxf(bhi(u0.y) * sc[3] + sh[3], 0.f) + fmaxf(bhi(u1.y) * sc[3] + sh[3], 0.f)
                + fmaxf(bhi(u2.y) * sc[3] + sh[3], 0.f) + fmaxf(bhi(u3.y) * sc[3] + sh[3], 0.f);
    }
    for (; i < e; i++) {
        int s = elist[i];
        uint2 u = *(const uint2*)(h1b + (size_t)s * 128 + c0);
        acc[0] += fmaxf(blo(u.x) * sc[0] + sh[0], 0.f);
        acc[1] += fmaxf(bhi(u.x) * sc[1] + sh[1], 0.f);
        acc[2] += fmaxf(blo(u.y) * sc[2] + sh[2], 0.f);
        acc[3] += fmaxf(bhi(u.y) * sc[3] + sh[3], 0.f);
    }
    float inv = (e > b) ? 1.0f / (float)(e - b) : 1.0f;
    uint2 ow;
    ow.x = cvt2(acc[0] * inv, acc[1] * inv);
    ow.y = cvt2(acc[2] * inv, acc[3] * inv);
    *(uint2*)(m2b + (size_t)n * 128 + c0) = ow;
}

// ---------------- SAGE layer 1 (fp32 VALU, K=32+32), writes h1b bf16 + stats ----------------
__global__ __launch_bounds__(256) void k_node_l1(
    const float* __restrict__ meanX, const float* __restrict__ x,
    const float* __restrict__ Wl, const float* __restrict__ Wr,
    const float* __restrict__ bias,
    short* __restrict__ outp, float* __restrict__ ssum, float* __restrict__ ssq)
{
    __shared__ __align__(16) float sWl[32][128];
    __shared__ __align__(16) float sWr[32][128];
    __shared__ __align__(16) float sA[32][36];
    __shared__ __align__(16) float sB[32][36];
    __shared__ float red[2][128], red2[2][128];
    int tid = threadIdx.x;
    int j = tid & 127, rg = tid >> 7;
    int r0 = blockIdx.x * 32;

    for (int f = tid * 4; f < 4096; f += 1024) {
        *(float4*)((float*)sWl + f) = *(const float4*)(Wl + f);
        *(float4*)((float*)sWr + f) = *(const float4*)(Wr + f);
    }
    {
        int r = tid >> 3, c = (tid & 7) * 4;
        *(float4*)(&sA[r][c]) = *(const float4*)(meanX + (size_t)(r0 + r) * 32 + c);
        *(float4*)(&sB[r][c]) = *(const float4*)(x + (size_t)(r0 + r) * 32 + c);
    }
    __syncthreads();

    float acc[16];
    #pragma unroll
    for (int r = 0; r < 16; r++) acc[r] = 0.0f;
    int rb = rg * 16;
    #pragma unroll
    for (int kq = 0; kq < 8; kq++) {
        int k = kq * 4;
        float wl0 = sWl[k][j], wl1 = sWl[k+1][j], wl2 = sWl[k+2][j], wl3 = sWl[k+3][j];
        float wr0 = sWr[k][j], wr1 = sWr[k+1][j], wr2 = sWr[k+2][j], wr3 = sWr[k+3][j];
        #pragma unroll
        for (int r = 0; r < 16; r++) {
            float4 a = *(float4*)(&sA[rb + r][k]);
            float4 b = *(float4*)(&sB[rb + r][k]);
            acc[r] += a.x*wl0 + a.y*wl1 + a.z*wl2 + a.w*wl3
                    + b.x*wr0 + b.y*wr1 + b.z*wr2 + b.w*wr3;
        }
    }
    float bj = bias[j];
    float s1 = 0.0f, s2 = 0.0f;
    #pragma unroll
    for (int r = 0; r < 16; r += 2) {
        float v0 = acc[r] + bj, v1 = acc[r + 1] + bj;
        s1 += v0 + v1; s2 += v0 * v0 + v1 * v1;
        unsigned p = cvt2(v0, v1);
        outp[(size_t)(r0 + rb + r) * 128 + j]     = (short)p;
        outp[(size_t)(r0 + rb + r + 1) * 128 + j] = (short)(p >> 16);
    }
    red[rg][j] = s1; red2[rg][j] = s2;
    __syncthreads();
    if (rg == 0) {
        atomicAdd(&ssum[j], red[0][j] + red[1][j]);
        atomicAdd(&ssq[j],  red2[0][j] + red2[1][j]);
    }
}

// ---------------- SAGE layer 2 via MFMA (bn1 inlined): h2 = [mean | bnrelu(h1)] @ W2c + b2 ----------------
__global__ __launch_bounds__(256) void k_node_l2m(
    const short* __restrict__ m2b, const short* __restrict__ h1b,
    const float* __restrict__ ssum1, const float* __restrict__ ssq1,
    const float* __restrict__ g1, const float* __restrict__ b1g,
    const short* __restrict__ W2cT, const float* __restrict__ bias,
    short* __restrict__ h2b, float* __restrict__ ssum, float* __restrict__ ssq)
{
    __shared__ __align__(16) short sK[32][264];
    __shared__ float sRed[2][128];
    __shared__ float sS[128], sH[128];
    const int tid = threadIdx.x;
    const int wave = tid >> 6, lane = tid & 63, quad = lane >> 4, ln = lane & 15;
    const int waveM = wave >> 1, waveN = wave & 1;
    const int colbase = 64 * waveN, row16 = 16 * waveM;
    if (tid < 128) {
        float m = ssum1[tid] / (float)NN;
        float var = ssq1[tid] / (float)NN - m * m;
        float rs = rsqrtf(var + 1e-5f);
        float s = g1[tid] * rs;
        sS[tid] = s; sH[tid] = b1g[tid] - m * s;
        sRed[0][tid] = 0.f; sRed[1][tid] = 0.f;
    }

    bf16x8 bW[4][8];
    #pragma unroll
    for (int nt = 0; nt < 4; nt++)
        #pragma unroll
        for (int kk = 0; kk < 8; kk++)
            bW[nt][kk] = *(const bf16x8*)(W2cT + (size_t)(colbase + nt * 16 + ln) * 256 + kk * 32 + quad * 8);
    float bc[4];
    #pragma unroll
    for (int nt = 0; nt < 4; nt++) bc[nt] = bias[colbase + nt * 16 + ln];

    float s1[4] = {0,0,0,0}, s2[4] = {0,0,0,0};
    f32x4 zero = {0.f, 0.f, 0.f, 0.f};
    __syncthreads();

    for (int t = blockIdx.x; t < NN / 32; t += gridDim.x) {
        int r0 = t * 32;
        __syncthreads();
        {
            int r = tid >> 3, seg = tid & 7;
            if (seg < 4) {
                const bf16x8* src = (const bf16x8*)(m2b + (size_t)(r0 + r) * 128 + seg * 32);
                bf16x8* dst = (bf16x8*)(&sK[r][seg * 32]);
                dst[0] = src[0]; dst[1] = src[1]; dst[2] = src[2]; dst[3] = src[3];
            } else {
                int c0 = (seg - 4) * 32;
                const uint4* pw = (const uint4*)(h1b + (size_t)(r0 + r) * 128 + c0);
                uint4* dw = (uint4*)(&sK[r][128 + c0]);
                #pragma unroll
                for (int i2 = 0; i2 < 4; i2++) {
                    uint4 u = pw[i2];
                    int cb = c0 + i2 * 8;
                    uint4 ow;
                    ow.x = cvt2(fmaxf(blo(u.x)*sS[cb+0]+sH[cb+0],0.f), fmaxf(bhi(u.x)*sS[cb+1]+sH[cb+1],0.f));
                    ow.y = cvt2(fmaxf(blo(u.y)*sS[cb+2]+sH[cb+2],0.f), fmaxf(bhi(u.y)*sS[cb+3]+sH[cb+3],0.f));
                    ow.z = cvt2(fmaxf(blo(u.z)*sS[cb+4]+sH[cb+4],0.f), fmaxf(bhi(u.z)*sS[cb+5]+sH[cb+5],0.f));
                    ow.w = cvt2(fmaxf(blo(u.w)*sS[cb+6]+sH[cb+6],0.f), fmaxf(bhi(u.w)*sS[cb+7]+sH[cb+7],0.f));
                    dw[i2] = ow;
                }
            }
        }
        __syncthreads();
        f32x4 acc[4] = {zero, zero, zero, zero};
        #pragma unroll
        for (int kk = 0; kk < 8; kk++) {
            bf16x8 a = *(const bf16x8*)(&sK[row16 + ln][kk * 32 + quad * 8]);
            #pragma unroll
            for (int nt = 0; nt < 4; nt++)
                acc[nt] = __builtin_amdgcn_mfma_f32_16x16x32_bf16(a, bW[nt][kk], acc[nt], 0, 0, 0);
        }
        #pragma unroll
        for (int nt = 0; nt < 4; nt++) {
            int col = colbase + nt * 16 + ln;
            float v0 = acc[nt][0] + bc[nt], v1 = acc[nt][1] + bc[nt];
            float v2 = acc[nt][2] + bc[nt], v3 = acc[nt][3] + bc[nt];
            s1[nt] += (v0 + v1) + (v2 + v3);
            s2[nt] += (v0*v0 + v1*v1) + (v2*v2 + v3*v3);
            unsigned p01 = cvt2(v0, v1), p23 = cvt2(v2, v3);
            h2b[(size_t)(r0 + row16 + quad * 4 + 0) * 128 + col] = (short)p01;
            h2b[(size_t)(r0 + row16 + quad * 4 + 1) * 128 + col] = (short)(p01 >> 16);
            h2b[(size_t)(r0 + row16 + quad * 4 + 2) * 128 + col] = (short)p23;
            h2b[(size_t)(r0 + row16 + quad * 4 + 3) * 128 + col] = (short)(p23 >> 16);
        }
    }
    #pragma unroll
    for (int nt = 0; nt < 4; nt++) {
        float a1 = s1[nt], a2 = s2[nt];
        a1 += __shfl_down(a1, 32); a1 += __shfl_down(a1, 16);
        a2 += __shfl_down(a2, 32); a2 += __shfl_down(a2, 16);
        if (quad == 0) {
            atomicAdd(&sRed[0][colbase + nt * 16 + ln], a1);
            atomicAdd(&sRed[1][colbase + nt * 16 + ln], a2);
        }
    }
    __syncthreads();
    if (tid < 128) {
        atomicAdd(&ssum[tid], sRed[0][tid]);
        atomicAdd(&ssq[tid],  sRed[1][tid]);
    }
}

// ---------------- node projection (bn2 inlined): both hs and hd in one launch ----------------
__global__ __launch_bounds__(256) void k_proj_mfma(
    const short* __restrict__ h2b,
    const float* __restrict__ ssum2, const float* __restrict__ ssq2,
    const float* __restrict__ g2, const float* __restrict__ b2g,
    const short* __restrict__ WT0, const short* __restrict__ WT1,
    short* __restrict__ C0, short* __restrict__ C1)
{
    __shared__ __align__(16) short sA[32][136];
    __shared__ float sS[128], sH[128];
    const int tid = threadIdx.x;
    const int wave = tid >> 6, lane = tid & 63, quad = lane >> 4, ln = lane & 15;
    const int waveM = wave >> 1, waveN = wave & 1;
    const int colbase = 64 * waveN, row16 = 16 * waveM;
    const int half = (blockIdx.x >= 512) ? 1 : 0;
    const short* WT = half ? WT1 : WT0;
    short* C = half ? C1 : C0;
    const int b0 = blockIdx.x - half * 512;
    if (tid < 128) {
        float m = ssum2[tid] / (float)NN;
        float var = ssq2[tid] / (float)NN - m * m;
        float rs = rsqrtf(var + 1e-5f);
        float s = g2[tid] * rs;
        sS[tid] = s; sH[tid] = b2g[tid] - m * s;
    }
    bf16x8 bW[4][4];
    #pragma unroll
    for (int nt = 0; nt < 4; nt++)
        #pragma unroll
        for (int kk = 0; kk < 4; kk++)
            bW[nt][kk] = *(const bf16x8*)(WT + (colbase + nt * 16 + ln) * 128 + kk * 32 + quad * 8);
    f32x4 zero = {0.f, 0.f, 0.f, 0.f};
    __syncthreads();
    for (int t = b0; t < NN / 32; t += 512) {
        int r0 = t * 32;
        __syncthreads();
        {
            int r = tid >> 3, c0 = (tid & 7) * 16;
            const uint4* pw = (const uint4*)(h2b + (size_t)(r0 + r) * 128 + c0);
            uint4* dw = (uint4*)(&sA[r][c0]);
            #pragma unroll
            for (int i2 = 0; i2 < 2; i2++) {
                uint4 u = pw[i2];
                int cb = c0 + i2 * 8;
                uint4 ow;
                ow.x = cvt2(fmaxf(blo(u.x)*sS[cb+0]+sH[cb+0],0.f), fmaxf(bhi(u.x)*sS[cb+1]+sH[cb+1],0.f));
                ow.y = cvt2(fmaxf(blo(u.y)*sS[cb+2]+sH[cb+2],0.f), fmaxf(bhi(u.y)*sS[cb+3]+sH[cb+3],0.f));
                ow.z = cvt2(fmaxf(blo(u.z)*sS[cb+4]+sH[cb+4],0.f), fmaxf(bhi(u.z)*sS[cb+5]+sH[cb+5],0.f));
                ow.w = cvt2(fmaxf(blo(u.w)*sS[cb+6]+sH[cb+6],0.f), fmaxf(bhi(u.w)*sS[cb+7]+sH[cb+7],0.f));
                dw[i2] = ow;
            }
        }
        __syncthreads();
        f32x4 acc[4] = {zero, zero, zero, zero};
        #pragma unroll
        for (int kk = 0; kk < 4; kk++) {
            bf16x8 a = *(const bf16x8*)(&sA[row16 + ln][kk * 32 + quad * 8]);
            #pragma unroll
            for (int nt = 0; nt < 4; nt++)
                acc[nt] = __builtin_amdgcn_mfma_f32_16x16x32_bf16(a, bW[nt][kk], acc[nt], 0, 0, 0);
        }
        #pragma unroll
        for (int nt = 0; nt < 4; nt++) {
            int col = colbase + nt * 16 + ln;
            unsigned p01 = cvt2(acc[nt][0], acc[nt][1]);
            unsigned p23 = cvt2(acc[nt][2], acc[nt][3]);
            C[(size_t)(r0 + row16 + quad * 4 + 0) * 128 + col] = (short)p01;
            C[(size_t)(r0 + row16 + quad * 4 + 1) * 128 + col] = (short)(p01 >> 16);
            C[(size_t)(r0 + row16 + quad * 4 + 2) * 128 + col] = (short)p23;
            C[(size_t)(r0 + row16 + quad * 4 + 3) * 128 + col] = (short)(p23 >> 16);
        }
    }
}

// ---------------- edge MODE1, 64-edge tiles, 512 threads (8 waves) ----------------
// v = relu(t@W1p + bm1p + hs[es] + hd[et]); bnm stats; store v. Pipelined as before,
// but 2 barriers per 64 edges instead of 4.
__global__ __launch_bounds__(512) void k_edge_m1(
    const float* __restrict__ ea,
    const short* __restrict__ WteT, const float* __restrict__ be,
    const short* __restrict__ W1pT, const float* __restrict__ bm1p,
    const short* __restrict__ hs, const short* __restrict__ hd,
    const int* __restrict__ esrc, const int* __restrict__ etgt,
    float* __restrict__ ssum, float* __restrict__ ssq,
    short* __restrict__ vbuf)
{
    __shared__ __align__(16) short sT[64][136];
    __shared__ __align__(16) float sSum[64][132];
    __shared__ float sRed[2][128];

    const int tid = threadIdx.x;
    const int wave = tid >> 6, lane = tid & 63;
    const int quad = lane >> 4, ln = lane & 15;
    const int waveM = wave >> 1, waveN = wave & 1;
    const int colbase = 64 * waveN, row16 = 16 * waveM;

    if (tid < 128) { sRed[0][tid] = 0.f; sRed[1][tid] = 0.f; }

    bf16x8 bWe[4], bW1[4][4];
    float bec[4], bmc[4];
    #pragma unroll
    for (int nt = 0; nt < 4; nt++) {
        bWe[nt] = *(const bf16x8*)(WteT + (colbase + nt * 16 + ln) * 32 + quad * 8);
        #pragma unroll
        for (int kk = 0; kk < 4; kk++)
            bW1[nt][kk] = *(const bf16x8*)(W1pT + (colbase + nt * 16 + ln) * 128 + kk * 32 + quad * 8);
        bec[nt] = be[colbase + nt * 16 + ln];
        bmc[nt] = bm1p[colbase + nt * 16 + ln];
    }

    // staging geometry: 8 threads per edge-row, 16 cols (2x16B per source) each
    const int srow = tid >> 3;          // 0..63
    const int scol = (tid & 7) * 16;    // 0..112

    float s1[4] = {0,0,0,0}, s2[4] = {0,0,0,0};
    f32x4 zero = {0.f, 0.f, 0.f, 0.f};

    const int G = gridDim.x;
    const int NT = NE / 64;
    bf16x8 gA0 = {}, gA1 = {}, gB0 = {}, gB1 = {};   // hs/hd halves for tile t
    int i1s = 0, i1t = 0;                             // indices for tile t+G
    float4 fe0 = {0,0,0,0}, fe1 = {0,0,0,0};          // eattr for tile t (quad<2)

    int t = blockIdx.x;
    if (t < NT) {
        const int e0 = t * 64;
        int s0 = esrc[e0 + srow], d0 = etgt[e0 + srow];
        const short* ph = hs + (size_t)s0 * 128 + scol;
        const short* pd = hd + (size_t)d0 * 128 + scol;
        gA0 = *(const bf16x8*)ph;       gA1 = *(const bf16x8*)(ph + 8);
        gB0 = *(const bf16x8*)pd;       gB1 = *(const bf16x8*)(pd + 8);
        int t1 = t + G;
        if (t1 < NT) {
            i1s = esrc[t1 * 64 + srow]; i1t = etgt[t1 * 64 + srow];
        }
        if (quad < 2) {
            const float* p = ea + (size_t)(e0 + row16 + ln) * 16 + quad * 8;
            fe0 = *(const float4*)p; fe1 = *(const float4*)(p + 4);
        }
    }

    for (; t < NT; t += G) {
        const int e0 = t * 64;

        // ---- t-GEMM from prefetched eattr ----
        bf16x8 aE;
        if (quad < 2) {
            uint4 uw;
            uw.x = cvt2(fe0.x, fe0.y); uw.y = cvt2(fe0.z, fe0.w);
            uw.z = cvt2(fe1.x, fe1.y); uw.w = cvt2(fe1.z, fe1.w);
            aE = *(bf16x8*)&uw;
        } else {
            #pragma unroll
            for (int i = 0; i < 8; i++) aE[i] = 0;
        }
        f32x4 tacc[4];
        #pragma unroll
        for (int nt = 0; nt < 4; nt++)
            tacc[nt] = __builtin_amdgcn_mfma_f32_16x16x32_bf16(aE, bWe[nt], zero, 0, 0, 0);

        __syncthreads();   // prev iteration finished reading sT/sSum

        // ---- write sT (packed cvt) ----
        #pragma unroll
        for (int nt = 0; nt < 4; nt++) {
            int col = colbase + nt * 16 + ln;
            unsigned p01 = cvt2(fmaxf(tacc[nt][0] + bec[nt], 0.f), fmaxf(tacc[nt][1] + bec[nt], 0.f));
            unsigned p23 = cvt2(fmaxf(tacc[nt][2] + bec[nt], 0.f), fmaxf(tacc[nt][3] + bec[nt], 0.f));
            sT[row16 + quad * 4 + 0][col] = (short)p01;
            sT[row16 + quad * 4 + 1][col] = (short)(p01 >> 16);
            sT[row16 + quad * 4 + 2][col] = (short)p23;
            sT[row16 + quad * 4 + 3][col] = (short)(p23 >> 16);
        }
        // ---- write sSum from in-flight gathers (word-wise unpack) ----
        {
            uint4 uA0 = *(const uint4*)&gA0, uB0 = *(const uint4*)&gB0;
            uint4 uA1 = *(const uint4*)&gA1, uB1 = *(const uint4*)&gB1;
            f32x4 q0, q1, q2, q3;
            q0[0] = blo(uA0.x) + blo(uB0.x); q0[1] = bhi(uA0.x) + bhi(uB0.x);
            q0[2] = blo(uA0.y) + blo(uB0.y); q0[3] = bhi(uA0.y) + bhi(uB0.y);
            q1[0] = blo(uA0.z) + blo(uB0.z); q1[1] = bhi(uA0.z) + bhi(uB0.z);
            q1[2] = blo(uA0.w) + blo(uB0.w); q1[3] = bhi(uA0.w) + bhi(uB0.w);
            q2[0] = blo(uA1.x) + blo(uB1.x); q2[1] = bhi(uA1.x) + bhi(uB1.x);
            q2[2] = blo(uA1.y) + blo(uB1.y); q2[3] = bhi(uA1.y) + bhi(uB1.y);
            q3[0] = blo(uA1.z) + blo(uB1.z); q3[1] = bhi(uA1.z) + bhi(uB1.z);
            q3[2] = blo(uA1.w) + blo(uB1.w); q3[3] = bhi(uA1.w) + bhi(uB1.w);
            *(f32x4*)(&sSum[srow][scol])      = q0;
            *(f32x4*)(&sSum[srow][scol + 4])  = q1;
            *(f32x4*)(&sSum[srow][scol + 8])  = q2;
            *(f32x4*)(&sSum[srow][scol + 12]) = q3;
        }
        // ---- prefetch next tile: gathers (idx resident), idx+2, eattr+1 ----
        {
            int t1 = t + G;
            if (t1 < NT) {
                const short* ph = hs + (size_t)i1s * 128 + scol;
                const short* pd = hd + (size_t)i1t * 128 + scol;
                gA0 = *(const bf16x8*)ph;   gA1 = *(const bf16x8*)(ph + 8);
                gB0 = *(const bf16x8*)pd;   gB1 = *(const bf16x8*)(pd + 8);
                int t2 = t1 + G;
                if (t2 < NT) {
                    i1s = esrc[t2 * 64 + srow]; i1t = etgt[t2 * 64 + srow];
                }
                if (quad < 2) {
                    const float* p = ea + (size_t)(t1 * 64 + row16 + ln) * 16 + quad * 8;
                    fe0 = *(const float4*)p; fe1 = *(const float4*)(p + 4);
                }
            }
        }
        __syncthreads();

        // ---- u-GEMM ----
        f32x4 uacc[4] = {zero, zero, zero, zero};
        #pragma unroll
        for (int kk = 0; kk < 4; kk++) {
            bf16x8 aU = *(const bf16x8*)(&sT[row16 + ln][kk * 32 + quad * 8]);
            #pragma unroll
            for (int nt = 0; nt < 4; nt++)
                uacc[nt] = __builtin_amdgcn_mfma_f32_16x16x32_bf16(aU, bW1[nt][kk], uacc[nt], 0, 0, 0);
        }
        // ---- v + stats + store (packed cvt) ----
        #pragma unroll
        for (int nt = 0; nt < 4; nt++) {
            int col = colbase + nt * 16 + ln;
            float v0 = fmaxf(uacc[nt][0] + bmc[nt] + sSum[row16 + quad * 4 + 0][col], 0.f);
            float v1 = fmaxf(uacc[nt][1] + bmc[nt] + sSum[row16 + quad * 4 + 1][col], 0.f);
            float v2 = fmaxf(uacc[nt][2] + bmc[nt] + sSum[row16 + quad * 4 + 2][col], 0.f);
            float v3 = fmaxf(uacc[nt][3] + bmc[nt] + sSum[row16 + quad * 4 + 3][col], 0.f);
            s1[nt] += (v0 + v1) + (v2 + v3);
            s2[nt] += (v0*v0 + v1*v1) + (v2*v2 + v3*v3);
            unsigned p01 = cvt2(v0, v1), p23 = cvt2(v2, v3);
            vbuf[(size_t)(e0 + row16 + quad * 4 + 0) * 128 + col] = (short)p01;
            vbuf[(size_t)(e0 + row16 + quad * 4 + 1) * 128 + col] = (short)(p01 >> 16);
            vbuf[(size_t)(e0 + row16 + quad * 4 + 2) * 128 + col] = (short)p23;
            vbuf[(size_t)(e0 + row16 + quad * 4 + 3) * 128 + col] = (short)(p23 >> 16);
        }
    }

    #pragma unroll
    for (int nt = 0; nt < 4; nt++) {
        float a1 = s1[nt], a2 = s2[nt];
        a1 += __shfl_down(a1, 32); a1 += __shfl_down(a1, 16);
        a2 += __shfl_down(a2, 32); a2 += __shfl_down(a2, 16);
        if (quad == 0) {
            atomicAdd(&sRed[0][colbase + nt * 16 + ln], a1);
            atomicAdd(&sRed[1][colbase + nt * 16 + ln], a2);
        }
    }
    __syncthreads();
    if (tid < 128) {
        atomicAdd(&ssum[tid], sRed[0][tid]);
        atomicAdd(&ssq[tid],  sRed[1][tid]);
    }
}

// ---------------- edge pipeline via MFMA (modes 2 & 3; mode 2 = non-storev fallback) ----------------
template<int MODE, bool STOREV = false>
__global__ __launch_bounds__(256) void k_edge_mfma(
    const float* __restrict__ ea,
    const short* __restrict__ WteT, const float* __restrict__ be,
    const short* __restrict__ W1pT, const float* __restrict__ bm1p,
    const short* __restrict__ hs, const short* __restrict__ hd,
    const int* __restrict__ esrc, const int* __restrict__ etgt,
    const float* __restrict__ Wm2, const float* __restrict__ bm2,
    const float* __restrict__ bnm_g, const float* __restrict__ bnm_b,
    const float* __restrict__ Wm3, const float* __restrict__ bm3,
    float* __restrict__ ssum, float* __restrict__ ssq,
    short* __restrict__ vbuf, float* __restrict__ outp)
{
    __shared__ __align__(16) short sT[32][136];
    __shared__ __align__(16) float sSum[32][132];
    __shared__ float sRed[2][128];
    __shared__ __align__(16) short sW2[64][136];
    __shared__ float sZ[32][69];                    // also scratch for inlined fold (preamble)
    __shared__ float sW3[64];

    const int tid = threadIdx.x;
    const int wave = tid >> 6, lane = tid & 63;
    const int quad = lane >> 4, ln = lane & 15;
    const int waveM = wave >> 1, waveN = wave & 1;
    const int colbase = 64 * waveN, row16 = 16 * waveM;

    if (MODE < 2) {
        if (tid < 128) { sRed[0][tid] = 0.f; sRed[1][tid] = 0.f; }
    }
    float b2c[2] = {0.f, 0.f};
    if (MODE >= 2) {
        // ---- inlined fold of bnm (from stats) into sW2 / b2 ----
        float* sSc   = (float*)sZ;          // 128
        float* sSh   = sSc + 128;           // 128
        float* sPart = sSh + 128;           // 256
        float* sB2   = sPart + 256;         // 64
        if (tid < 128) {
            float m = ssum[tid] / (float)NE;
            float var = ssq[tid] / (float)NE - m * m;
            float rs = rsqrtf(var + 1e-5f);
            float a = bnm_g[tid] * rs;
            sSc[tid] = a; sSh[tid] = bnm_b[tid] - m * a;
        }
        if (tid < 64) sW3[tid] = Wm3[tid];
        __syncthreads();
        {
            int col = tid & 63, kg = tid >> 6;
            float acc = 0.f;
            for (int k = kg * 32; k < kg * 32 + 32; k++) {
                float w = Wm2[k * 64 + col];
                sW2[col][k] = f2b(sSc[k] * w);
                acc += sSh[k] * w;
            }
            sPart[kg * 64 + col] = acc;
        }
        __syncthreads();
        if (tid < 64)
            ((float*)sZ)[512 + tid] = bm2[tid] + sPart[tid] + sPart[64 + tid]
                                    + sPart[128 + tid] + sPart[192 + tid];
        __syncthreads();
        b2c[0] = sB2[32 * waveN + ln];
        b2c[1] = sB2[32 * waveN + 16 + ln];
    }

    bf16x8 bWe[4], bW1[4][4];
    if (MODE <= 2) {
        #pragma unroll
        for (int nt = 0; nt < 4; nt++) {
            bWe[nt] = *(const bf16x8*)(WteT + (colbase + nt * 16 + ln) * 32 + quad * 8);
            if (MODE >= 1) {
                #pragma unroll
                for (int kk = 0; kk < 4; kk++)
                    bW1[nt][kk] = *(const bf16x8*)(W1pT + (colbase + nt * 16 + ln) * 128 + kk * 32 + quad * 8);
            }
        }
    }
    float bec[4], bmc[4];
    #pragma unroll
    for (int nt = 0; nt < 4; nt++) {
        bec[nt] = (MODE <= 2) ? be[colbase + nt * 16 + ln] : 0.f;
        bmc[nt] = (MODE == 1 || MODE == 2) ? bm1p[colbase + nt * 16 + ln] : 0.f;
    }
    float bm3v = (MODE >= 2) ? bm3[0] : 0.f;

    const int srow = tid >> 4;          // 0..15
    const int scol = (tid & 15) * 8;    // 0..120

    float s1[4] = {0,0,0,0}, s2[4] = {0,0,0,0};
    f32x4 zero = {0.f, 0.f, 0.f, 0.f};
    __syncthreads();

    if constexpr (MODE == 3) {
        // ---------------- pipelined MODE 3: vbuf prefetch ----------------
        const int G = gridDim.x;
        const int NT = NE / 32;
        bf16x8 aV0 = {}, aV1 = {}, aV2 = {}, aV3 = {};
        int t = blockIdx.x;
        if (t < NT) {
            const short* p = vbuf + (size_t)(t * 32 + row16 + ln) * 128 + quad * 8;
            aV0 = *(const bf16x8*)(p);
            aV1 = *(const bf16x8*)(p + 32);
            aV2 = *(const bf16x8*)(p + 64);
            aV3 = *(const bf16x8*)(p + 96);
        }
        for (; t < NT; t += G) {
            const int e0 = t * 32;
            f32x4 vacc[2] = {zero, zero};
            #pragma unroll
            for (int n2 = 0; n2 < 2; n2++) {
                bf16x8 bV0 = *(const bf16x8*)(&sW2[32 * waveN + n2 * 16 + ln][0 * 32 + quad * 8]);
                bf16x8 bV1 = *(const bf16x8*)(&sW2[32 * waveN + n2 * 16 + ln][1 * 32 + quad * 8]);
                bf16x8 bV2 = *(const bf16x8*)(&sW2[32 * waveN + n2 * 16 + ln][2 * 32 + quad * 8]);
                bf16x8 bV3 = *(const bf16x8*)(&sW2[32 * waveN + n2 * 16 + ln][3 * 32 + quad * 8]);
                vacc[n2] = __builtin_amdgcn_mfma_f32_16x16x32_bf16(aV0, bV0, vacc[n2], 0, 0, 0);
                vacc[n2] = __builtin_amdgcn_mfma_f32_16x16x32_bf16(aV1, bV1, vacc[n2], 0, 0, 0);
                vacc[n2] = __builtin_amdgcn_mfma_f32_16x16x32_bf16(aV2, bV2, vacc[n2], 0, 0, 0);
                vacc[n2] = __builtin_amdgcn_mfma_f32_16x16x32_bf16(aV3, bV3, vacc[n2], 0, 0, 0);
            }
            {
                int t1 = t + G;
                if (t1 < NT) {
                    const short* p = vbuf + (size_t)(t1 * 32 + row16 + ln) * 128 + quad * 8;
                    aV0 = *(const bf16x8*)(p);
                    aV1 = *(const bf16x8*)(p + 32);
                    aV2 = *(const bf16x8*)(p + 64);
                    aV3 = *(const bf16x8*)(p + 96);
                }
            }
            __syncthreads();
            #pragma unroll
            for (int n2 = 0; n2 < 2; n2++) {
                int col2 = 32 * waveN + n2 * 16 + ln;
                #pragma unroll
                for (int r = 0; r < 4; r++)
                    sZ[row16 + quad * 4 + r][col2] = fmaxf(vacc[n2][r] + b2c[n2], 0.f);
            }
            __syncthreads();
            {
                int row = wave * 8 + (lane >> 3);
                int ks  = (lane & 7) * 8;
                float o = 0.f;
                #pragma unroll
                for (int k2 = 0; k2 < 8; k2++)
                    o += sZ[row][ks + k2] * sW3[ks + k2];
                o += __shfl_xor(o, 1);
                o += __shfl_xor(o, 2);
                o += __shfl_xor(o, 4);
                if ((lane & 7) == 0) outp[e0 + row] = o + bm3v;
            }
        }
    } else if constexpr (MODE == 2) {
    // ---------------- MODE 2 fallback (recompute path) ----------------
    for (int t = blockIdx.x; t < NE / 32; t += gridDim.x) {
        const int e0 = t * 32;

        int isA = esrc[e0 + srow],      itA = etgt[e0 + srow];
        int isB = esrc[e0 + srow + 16], itB = etgt[e0 + srow + 16];

        bf16x8 aE;
        if (quad < 2) {
            const float* p = ea + (size_t)(e0 + row16 + ln) * 16 + quad * 8;
            float4 f0 = *(const float4*)p, f1 = *(const float4*)(p + 4);
            uint4 uw;
            uw.x = cvt2(f0.x, f0.y); uw.y = cvt2(f0.z, f0.w);
            uw.z = cvt2(f1.x, f1.y); uw.w = cvt2(f1.z, f1.w);
            aE = *(bf16x8*)&uw;
        } else {
            #pragma unroll
            for (int i = 0; i < 8; i++) aE[i] = 0;
        }
        f32x4 tacc[4];
        #pragma unroll
        for (int nt = 0; nt < 4; nt++)
            tacc[nt] = __builtin_amdgcn_mfma_f32_16x16x32_bf16(aE, bWe[nt], zero, 0, 0, 0);

        __syncthreads();
        {
            bf16x8 gA = *(const bf16x8*)(hs + (size_t)isA * 128 + scol);
            bf16x8 gB = *(const bf16x8*)(hd + (size_t)itA * 128 + scol);
            bf16x8 gC = *(const bf16x8*)(hs + (size_t)isB * 128 + scol);
            bf16x8 gD = *(const bf16x8*)(hd + (size_t)itB * 128 + scol);
            #pragma unroll
            for (int nt = 0; nt < 4; nt++) {
                int col = colbase + nt * 16 + ln;
                unsigned p01 = cvt2(fmaxf(tacc[nt][0] + bec[nt], 0.f), fmaxf(tacc[nt][1] + bec[nt], 0.f));
                unsigned p23 = cvt2(fmaxf(tacc[nt][2] + bec[nt], 0.f), fmaxf(tacc[nt][3] + bec[nt], 0.f));
                sT[row16 + quad * 4 + 0][col] = (short)p01;
                sT[row16 + quad * 4 + 1][col] = (short)(p01 >> 16);
                sT[row16 + quad * 4 + 2][col] = (short)p23;
                sT[row16 + quad * 4 + 3][col] = (short)(p23 >> 16);
            }
            uint4 uA = *(const uint4*)&gA, uB = *(const uint4*)&gB;
            uint4 uC = *(const uint4*)&gC, uD = *(const uint4*)&gD;
            f32x4 a0, a1, b0, b1;
            a0[0] = blo(uA.x) + blo(uB.x); a0[1] = bhi(uA.x) + bhi(uB.x);
            a0[2] = blo(uA.y) + blo(uB.y); a0[3] = bhi(uA.y) + bhi(uB.y);
            a1[0] = blo(uA.z) + blo(uB.z); a1[1] = bhi(uA.z) + bhi(uB.z);
            a1[2] = blo(uA.w) + blo(uB.w); a1[3] = bhi(uA.w) + bhi(uB.w);
            b0[0] = blo(uC.x) + blo(uD.x); b0[1] = bhi(uC.x) + bhi(uD.x);
            b0[2] = blo(uC.y) + blo(uD.y); b0[3] = bhi(uC.y) + bhi(uD.y);
            b1[0] = blo(uC.z) + blo(uD.z); b1[1] = bhi(uC.z) + bhi(uD.z);
            b1[2] = blo(uC.w) + blo(uD.w); b1[3] = bhi(uC.w) + bhi(uD.w);
            *(f32x4*)(&sSum[srow][scol])          = a0;
            *(f32x4*)(&sSum[srow][scol + 4])      = a1;
            *(f32x4*)(&sSum[srow + 16][scol])     = b0;
            *(f32x4*)(&sSum[srow + 16][scol + 4]) = b1;
        }
        __syncthreads();

        f32x4 uacc[4] = {zero, zero, zero, zero};
        #pragma unroll
        for (int kk = 0; kk < 4; kk++) {
            bf16x8 aU = *(const bf16x8*)(&sT[row16 + ln][kk * 32 + quad * 8]);
            #pragma unroll
            for (int nt = 0; nt < 4; nt++)
                uacc[nt] = __builtin_amdgcn_mfma_f32_16x16x32_bf16(aU, bW1[nt][kk], uacc[nt], 0, 0, 0);
        }

        __syncthreads();
        #pragma unroll
        for (int nt = 0; nt < 4; nt++) {
            int col = colbase + nt * 16 + ln;
            #pragma unroll
            for (int r = 0; r < 4; r++) {
                float v = uacc[nt][r] + bmc[nt] + sSum[row16 + quad * 4 + r][col];
                sT[row16 + quad * 4 + r][col] = f2b(fmaxf(v, 0.f));
            }
        }
        __syncthreads();
        f32x4 vacc[2] = {zero, zero};
        #pragma unroll
        for (int kk = 0; kk < 4; kk++) {
            bf16x8 aV = *(const bf16x8*)(&sT[row16 + ln][kk * 32 + quad * 8]);
            #pragma unroll
            for (int n2 = 0; n2 < 2; n2++) {
                bf16x8 bV = *(const bf16x8*)(&sW2[32 * waveN + n2 * 16 + ln][kk * 32 + quad * 8]);
                vacc[n2] = __builtin_amdgcn_mfma_f32_16x16x32_bf16(aV, bV, vacc[n2], 0, 0, 0);
            }
        }
        #pragma unroll
        for (int n2 = 0; n2 < 2; n2++) {
            int col2 = 32 * waveN + n2 * 16 + ln;
            #pragma unroll
            for (int r = 0; r < 4; r++)
                sZ[row16 + quad * 4 + r][col2] = fmaxf(vacc[n2][r] + b2c[n2], 0.f);
        }
        __syncthreads();
        {
            int row = wave * 8 + (lane >> 3);
            int ks  = (lane & 7) * 8;
            float o = 0.f;
            #pragma unroll
            for (int k2 = 0; k2 < 8; k2++)
                o += sZ[row][ks + k2] * sW3[ks + k2];
            o += __shfl_xor(o, 1);
            o += __shfl_xor(o, 2);
            o += __shfl_xor(o, 4);
            if ((lane & 7) == 0) outp[e0 + row] = o + bm3v;
        }
    }
    }  // end MODE dispatch

    if (MODE < 2) {
        #pragma unroll
        for (int nt = 0; nt < 4; nt++) {
            float a1 = s1[nt], a2 = s2[nt];
            a1 += __shfl_down(a1, 32); a1 += __shfl_down(a1, 16);
            a2 += __shfl_down(a2, 32); a2 += __shfl_down(a2, 16);
            if (quad == 0) {
                atomicAdd(&sRed[0][colbase + nt * 16 + ln], a1);
                atomicAdd(&sRed[1][colbase + nt * 16 + ln], a2);
            }
        }
        __syncthreads();
        if (tid < 128) {
            atomicAdd(&ssum[tid], sRed[0][tid]);
            atomicAdd(&ssq[tid],  sRed[1][tid]);
        }
    }
}

extern "C" void kernel_launch(void* const* d_in, const int* in_sizes, int n_in,
                              void* d_out, int out_size, void* d_ws, size_t ws_size,
                              hipStream_t stream) {
    const float* x     = (const float*)d_in[0];
    const int*   ei    = (const int*)  d_in[1];
    const float* eattr = (const float*)d_in[2];
    const int*   esrc  = (const int*)  d_in[3];
    const int*   etgt  = (const int*)  d_in[4];
    const float* W1l = (const float*)d_in[5];  const float* b1 = (const float*)d_in[6];
    const float* W1r = (const float*)d_in[7];
    const float* W2l = (const float*)d_in[8];  const float* b2 = (const float*)d_in[9];
    const float* W2r = (const float*)d_in[10];
    const float* bn1_g = (const float*)d_in[11]; const float* bn1_b = (const float*)d_in[12];
    const float* bn2_g = (const float*)d_in[13]; const float* bn2_b = (const float*)d_in[14];
    const float* We  = (const float*)d_in[15]; const float* be  = (const float*)d_in[16];
    const float* bne_g = (const float*)d_in[17]; const float* bne_b = (const float*)d_in[18];
    const float* Wm1 = (const float*)d_in[19]; const float* bm1 = (const float*)d_in[20];
    const float* bnm_g = (const float*)d_in[21]; const float* bnm_b = (const float*)d_in[22];
    const float* Wm2 = (const float*)d_in[23]; const float* bm2 = (const float*)d_in[24];
    const float* Wm3 = (const float*)d_in[25]; const float* bm3 = (const float*)d_in[26];
    float* out = (float*)d_out;

    char* base = (char*)d_ws;
    size_t o = 0;
    auto A = [&](size_t bytes) { char* p = base + o; o = (o + bytes + 255) & ~(size_t)255; return p; };
    short* hsb   = (short*)A((size_t)NN * 128 * 2);
    short* hdb   = (short*)A((size_t)NN * 128 * 2);
    int*   deg   = (int*)  A((size_t)NN * 4);
    int*   rowptr= (int*)  A((size_t)(NN + 1) * 4);
    int*   wp    = (int*)  A((size_t)NN * 4);
    int*   elist = (int*)  A((size_t)NE * 4);
    float* st    = (float*)A(1024 * 4);
    int*   bsum  = (int*)  A(SCAN_NB * 4);
    int*   boff  = (int*)  A(SCAN_NB * 4);
    float* sc1   = (float*)A(512); float* sh1 = (float*)A(512);
    float* sc2   = (float*)A(512); float* sh2 = (float*)A(512);
    float* bm1p  = (float*)A(512); float* b2p = (float*)A(256);
    short* WteT  = (short*)A(128 * 32 * 2);
    short* W1pT  = (short*)A(128 * 128 * 2);
    short* WmsT  = (short*)A(128 * 128 * 2);
    short* WmdT  = (short*)A(128 * 128 * 2);
    short* W2pT  = (short*)A(64 * 128 * 2);
    short* W2cT  = (short*)A(128 * 256 * 2);
    size_t chain = o;
    float* meanX = (float*)A((size_t)NN * 32 * 4);
    short* h1b   = (short*)A((size_t)NN * 128 * 2);
    short* m2b   = (short*)A((size_t)NN * 128 * 2);
    short* h2b   = (short*)A((size_t)NN * 128 * 2);
    int*   stmp  = (int*)meanX;                         // scan tmp aliases meanX (dead until gagg1)
    short* vbuf  = (short*)(base + chain);              // aliases meanX..h2b (all dead by then)
    bool storev = ws_size >= chain + (size_t)NE * 128 * 2;
    (void)W2pT; (void)b2p; (void)sc1; (void)sh1; (void)sc2; (void)sh2;

    hipMemsetAsync(deg, 0, (size_t)NN * 4, stream);
    hipMemsetAsync(st, 0, 1024 * 4, stream);

    // weight prep + degree histogram (fused), then 3-phase scan
    k_prep_hist<<<5 + (NE + 255) / 256, 256, 0, stream>>>(We, Wm1, W2l, W2r,
        WteT, WmsT, WmdT, W2cT, ei, deg);
    k_scan_a<<<SCAN_NB, 1024, 0, stream>>>(deg, stmp, bsum);
    k_scan_b<<<1, 64, 0, stream>>>(bsum, boff, rowptr);
    k_scan_c<<<SCAN_NB, 1024, 0, stream>>>(stmp, boff, rowptr, wp);

    // CSR scatter + edge bne stats (fused, independent work overlapped)
    k_scat_e0<<<SCAT_NB + 2048, 256, 0, stream>>>(ei, wp, elist,
        eattr, WteT, be, st + 512, st + 640);

    // ---- layer 1: gather-mean + fold_e (fused) ----
    k_gagg1f<<<NN / 8 + 1, 256, 0, stream>>>(x, rowptr, elist, meanX,
        st + 512, st + 640, bne_g, bne_b, Wm1, bm1, W1pT, bm1p);
    k_node_l1<<<NN / 32, 256, 0, stream>>>(meanX, x, W1l, W1r, b1, h1b, st + 0, st + 128);

    // ---- layer 2 (bn1 inlined into consumers) ----
    k_gagg2<<<NN / 8, 256, 0, stream>>>(h1b, rowptr, elist, st + 0, st + 128, bn1_g, bn1_b, m2b);
    k_node_l2m<<<512, 256, 0, stream>>>(m2b, h1b, st + 0, st + 128, bn1_g, bn1_b,
        W2cT, b2, h2b, st + 256, st + 384);

    // ---- node projections (bn2 inlined; both in one launch) ----
    k_proj_mfma<<<1024, 256, 0, stream>>>(h2b, st + 256, st + 384, bn2_g, bn2_b,
        WmsT, WmdT, hsb, hdb);

    // ---- edge main ----
    if (storev)
        // 512 blocks x 512 thr = 2 blocks/CU (LDS 52.2KB, VGPR<=128), 64-edge tiles
        k_edge_m1<<<512, 512, 0, stream>>>(eattr, WteT, be, W1pT, bm1p, hsb, hdb,
            esrc, etgt, st + 768, st + 896, vbuf);
    else
        k_edge_mfma<2><<<1024, 256, 0, stream>>>(eattr, WteT, be, W1pT, bm1p, hsb, hdb,
            esrc, etgt, Wm2, bm2, bnm_g, bnm_b, Wm3, bm3, st + 768, st + 896, nullptr, out);

    // ---- edge final (fold of bnm inlined in preamble; 1536 = 6 blocks/CU LDS-bound) ----
    if (storev)
        k_edge_mfma<3><<<1536, 256, 0, stream>>>(eattr, WteT, be, W1pT, bm1p, hsb, hdb,
            esrc, etgt, Wm2, bm2, bnm_g, bnm_b, Wm3, bm3, st + 768, st + 896, vbuf, out);
}

// Round 9
// 708.765 us; speedup vs baseline: 1.0124x; 1.0124x over previous
//
#include <hip/hip_runtime.h>
#include <hip/hip_bf16.h>

#define NN 100000
#define NE 800000
#define SCAN_NB 98   // ceil(NN / 1024)

typedef __attribute__((ext_vector_type(8))) short bf16x8;
typedef __attribute__((ext_vector_type(4))) float f32x4;

__device__ __forceinline__ short f2b(float f) {
    unsigned u = __float_as_uint(f);
    unsigned r = (u + 0x7fffu + ((u >> 16) & 1u)) >> 16;
    return (short)r;
}
__device__ __forceinline__ float b2f(short s) {
    return __uint_as_float(((unsigned)(unsigned short)s) << 16);
}
// packed RNE f32x2 -> bf16x2 (lo=a, hi=b); bit-identical to f2b
__device__ __forceinline__ unsigned cvt2(float a, float b) {
    unsigned r;
    asm("v_cvt_pk_bf16_f32 %0, %1, %2" : "=v"(r) : "v"(a), "v"(b));
    return r;
}
__device__ __forceinline__ float blo(unsigned u) { return __uint_as_float(u << 16); }
__device__ __forceinline__ float bhi(unsigned u) { return __uint_as_float(u & 0xffff0000u); }

// ---------------- fused: weight prep (blocks 0..4) + degree histogram (blocks 5..) ----------------
__global__ __launch_bounds__(256) void k_prep_hist(
    const float* __restrict__ We, const float* __restrict__ Wm1,
    const float* __restrict__ W2l, const float* __restrict__ W2r,
    short* __restrict__ WteT, short* __restrict__ WmsT,
    short* __restrict__ WmdT, short* __restrict__ W2cT,
    const int* __restrict__ ei, int* __restrict__ deg)
{
    int b = blockIdx.x;
    int tid = threadIdx.x;
    if (b >= 5) {
        int e = (b - 5) * 256 + tid;
        if (e < NE) atomicAdd(&deg[ei[NE + e]], 1);
        return;
    }
    if (tid >= 128) return;
    int j = tid;
    if (b == 0) {
        for (int k = 0; k < 32; k++)
            WteT[j * 32 + k] = (k < 16) ? f2b(We[k * 128 + j]) : (short)0;
    } else if (b == 1) {
        for (int k = 0; k < 128; k++) WmsT[j * 128 + k] = f2b(Wm1[k * 128 + j]);
    } else if (b == 2) {
        for (int k = 0; k < 128; k++) WmdT[j * 128 + k] = f2b(Wm1[(128 + k) * 128 + j]);
    } else if (b == 3) {
        for (int k = 0; k < 128; k++) W2cT[j * 256 + k] = f2b(W2l[k * 128 + j]);
    } else {
        for (int k = 0; k < 128; k++) W2cT[j * 256 + 128 + k] = f2b(W2r[k * 128 + j]);
    }
}

// phase a: per-block exclusive scan (coalesced), block sums out
__global__ __launch_bounds__(1024) void k_scan_a(const int* __restrict__ deg,
    int* __restrict__ tmp, int* __restrict__ bsum)
{
    __shared__ int sh[1024];
    int t = threadIdx.x, b = blockIdx.x;
    int idx = b * 1024 + t;
    int v = (idx < NN) ? deg[idx] : 0;
    sh[t] = v;
    __syncthreads();
    for (int ofs = 1; ofs < 1024; ofs <<= 1) {
        int u = (t >= ofs) ? sh[t - ofs] : 0;
        __syncthreads();
        sh[t] += u;
        __syncthreads();
    }
    if (idx < NN) tmp[idx] = sh[t] - v;   // exclusive within block
    if (t == 1023) bsum[b] = sh[1023];
}

__global__ void k_scan_b(const int* __restrict__ bsum, int* __restrict__ boff,
    int* __restrict__ rowptr)
{
    if (threadIdx.x == 0) {
        int acc = 0;
        for (int i = 0; i < SCAN_NB; i++) { boff[i] = acc; acc += bsum[i]; }
        rowptr[NN] = acc;
    }
}

__global__ __launch_bounds__(1024) void k_scan_c(const int* __restrict__ tmp,
    const int* __restrict__ boff, int* __restrict__ rowptr, int* __restrict__ wp)
{
    int b = blockIdx.x, t = threadIdx.x;
    int idx = b * 1024 + t;
    if (idx < NN) {
        int v = boff[b] + tmp[idx];
        rowptr[idx] = v; wp[idx] = v;
    }
}

// ---------------- fused: CSR scatter (blocks 0..3124) + edge bne stats (blocks 3125..) ----------------
#define SCAT_NB 3125
__global__ __launch_bounds__(256) void k_scat_e0(
    const int* __restrict__ ei, int* __restrict__ wp, int* __restrict__ elist,
    const float* __restrict__ ea, const short* __restrict__ WteT, const float* __restrict__ be,
    float* __restrict__ ssum, float* __restrict__ ssq)
{
    const int tid = threadIdx.x;
    if (blockIdx.x < SCAT_NB) {
        int e = blockIdx.x * 256 + tid;
        if (e < NE) {
            int d = ei[NE + e];
            int pos = atomicAdd(&wp[d], 1);
            elist[pos] = ei[e];
        }
        return;
    }
    // ---- mode0: bne stats of t = relu(ea@We+be), eattr pipelined ----
    __shared__ float sRed[2][128];
    const int wave = tid >> 6, lane = tid & 63;
    const int quad = lane >> 4, ln = lane & 15;
    const int waveM = wave >> 1, waveN = wave & 1;
    const int colbase = 64 * waveN, row16 = 16 * waveM;
    if (tid < 128) { sRed[0][tid] = 0.f; sRed[1][tid] = 0.f; }

    bf16x8 bWe[4];
    float bec[4];
    #pragma unroll
    for (int nt = 0; nt < 4; nt++) {
        bWe[nt] = *(const bf16x8*)(WteT + (colbase + nt * 16 + ln) * 32 + quad * 8);
        bec[nt] = be[colbase + nt * 16 + ln];
    }
    float s1[4] = {0,0,0,0}, s2[4] = {0,0,0,0};
    f32x4 zero = {0.f, 0.f, 0.f, 0.f};
    __syncthreads();

    const int G = gridDim.x - SCAT_NB;
    const int NT = NE / 32;
    float4 fe0 = {0,0,0,0}, fe1 = {0,0,0,0};
    int t = blockIdx.x - SCAT_NB;
    if (t < NT && quad < 2) {
        const float* p = ea + (size_t)(t * 32 + row16 + ln) * 16 + quad * 8;
        fe0 = *(const float4*)p; fe1 = *(const float4*)(p + 4);
    }
    for (; t < NT; t += G) {
        bf16x8 aE;
        if (quad < 2) {
            uint4 uw;
            uw.x = cvt2(fe0.x, fe0.y); uw.y = cvt2(fe0.z, fe0.w);
            uw.z = cvt2(fe1.x, fe1.y); uw.w = cvt2(fe1.z, fe1.w);
            aE = *(bf16x8*)&uw;
        } else {
            #pragma unroll
            for (int i = 0; i < 8; i++) aE[i] = 0;
        }
        int t1 = t + G;
        if (t1 < NT && quad < 2) {
            const float* p = ea + (size_t)(t1 * 32 + row16 + ln) * 16 + quad * 8;
            fe0 = *(const float4*)p; fe1 = *(const float4*)(p + 4);
        }
        f32x4 tacc[4];
        #pragma unroll
        for (int nt = 0; nt < 4; nt++)
            tacc[nt] = __builtin_amdgcn_mfma_f32_16x16x32_bf16(aE, bWe[nt], zero, 0, 0, 0);
        #pragma unroll
        for (int nt = 0; nt < 4; nt++)
            #pragma unroll
            for (int r = 0; r < 4; r++) {
                float v = fmaxf(tacc[nt][r] + bec[nt], 0.f);
                s1[nt] += v; s2[nt] += v * v;
            }
    }
    #pragma unroll
    for (int nt = 0; nt < 4; nt++) {
        float a1 = s1[nt], a2 = s2[nt];
        a1 += __shfl_down(a1, 32); a1 += __shfl_down(a1, 16);
        a2 += __shfl_down(a2, 32); a2 += __shfl_down(a2, 16);
        if (quad == 0) {
            atomicAdd(&sRed[0][colbase + nt * 16 + ln], a1);
            atomicAdd(&sRed[1][colbase + nt * 16 + ln], a2);
        }
    }
    __syncthreads();
    if (tid < 128) {
        atomicAdd(&ssum[tid], sRed[0][tid]);
        atomicAdd(&ssq[tid],  sRed[1][tid]);
    }
}

// ---------------- fused: gather-mean layer1 (blocks 0..12499) + fold_e (block 12500) ----------------
__global__ __launch_bounds__(256) void k_gagg1f(const float* __restrict__ x,
    const int* __restrict__ rowptr, const int* __restrict__ elist, float* __restrict__ meanX,
    const float* __restrict__ essum, const float* __restrict__ essq,
    const float* __restrict__ bne_g, const float* __restrict__ bne_b,
    const float* __restrict__ Wm1, const float* __restrict__ bm1,
    short* __restrict__ W1pT, float* __restrict__ bm1p)
{
    if (blockIdx.x == NN / 8) {
        __shared__ float sa[128], scc[128];
        int tid = threadIdx.x;
        if (tid < 128) {
            float m = essum[tid] / (float)NE;
            float var = essq[tid] / (float)NE - m * m;
            float rs = rsqrtf(var + 1e-5f);
            float a = bne_g[tid] * rs;
            sa[tid] = a; scc[tid] = bne_b[tid] - m * a;
        }
        __syncthreads();
        if (tid < 128) {
            float acc = bm1[tid];
            for (int k = 0; k < 128; k++) {
                float w = Wm1[(256 + k) * 128 + tid];
                W1pT[tid * 128 + k] = f2b(sa[k] * w);
                acc += scc[k] * w;
            }
            bm1p[tid] = acc;
        }
        return;
    }
    int n = blockIdx.x * 8 + (threadIdx.x >> 5);
    int j = threadIdx.x & 31;
    int b = rowptr[n], e = rowptr[n + 1];
    float acc = 0.f;
    int i = b;
    for (; i + 4 <= e; i += 4) {
        int s0 = elist[i], s1 = elist[i + 1], s2 = elist[i + 2], s3 = elist[i + 3];
        float a0 = x[(size_t)s0 * 32 + j];
        float a1 = x[(size_t)s1 * 32 + j];
        float a2 = x[(size_t)s2 * 32 + j];
        float a3 = x[(size_t)s3 * 32 + j];
        acc += (a0 + a1) + (a2 + a3);
    }
    for (; i < e; i++) acc += x[(size_t)elist[i] * 32 + j];
    float inv = (e > b) ? 1.0f / (float)(e - b) : 1.0f;
    meanX[(size_t)n * 32 + j] = acc * inv;
}

// ---------------- gagg2: gather-mean of bnrelu(h1) (bn1 inlined from stats) ----------------
__global__ __launch_bounds__(256) void k_gagg2(const short* __restrict__ h1b,
    const int* __restrict__ rowptr, const int* __restrict__ elist,
    const float* __restrict__ ssum1, const float* __restrict__ ssq1,
    const float* __restrict__ g1, const float* __restrict__ b1g, short* __restrict__ m2b)
{
    int n = blockIdx.x * 8 + (threadIdx.x >> 5);
    int c0 = (threadIdx.x & 31) * 4;
    float sc[4], sh[4];
    #pragma unroll
    for (int i = 0; i < 4; i++) {
        float m = ssum1[c0 + i] / (float)NN;
        float var = ssq1[c0 + i] / (float)NN - m * m;
        float rs = rsqrtf(var + 1e-5f);
        float s = g1[c0 + i] * rs;
        sc[i] = s; sh[i] = b1g[c0 + i] - m * s;
    }
    int b = rowptr[n], e = rowptr[n + 1];
    float acc[4] = {0.f, 0.f, 0.f, 0.f};
    int i = b;
    for (; i + 4 <= e; i += 4) {
        int s0 = elist[i], s1 = elist[i + 1], s2 = elist[i + 2], s3 = elist[i + 3];
        uint2 u0 = *(const uint2*)(h1b + (size_t)s0 * 128 + c0);
        uint2 u1 = *(const uint2*)(h1b + (size_t)s1 * 128 + c0);
        uint2 u2 = *(const uint2*)(h1b + (size_t)s2 * 128 + c0);
        uint2 u3 = *(const uint2*)(h1b + (size_t)s3 * 128 + c0);
        acc[0] += fmaxf(blo(u0.x) * sc[0] + sh[0], 0.f) + fmaxf(blo(u1.x) * sc[0] + sh[0], 0.f)
                + fmaxf(blo(u2.x) * sc[0] + sh[0], 0.f) + fmaxf(blo(u3.x) * sc[0] + sh[0], 0.f);
        acc[1] += fmaxf(bhi(u0.x) * sc[1] + sh[1], 0.f) + fmaxf(bhi(u1.x) * sc[1] + sh[1], 0.f)
                + fmaxf(bhi(u2.x) * sc[1] + sh[1], 0.f) + fmaxf(bhi(u3.x) * sc[1] + sh[1], 0.f);
        acc[2] += fmaxf(blo(u0.y) * sc[2] + sh[2], 0.f) + fmaxf(blo(u1.y) * sc[2] + sh[2], 0.f)
                + fmaxf(blo(u2.y) * sc[2] + sh[2], 0.f) + fmaxf(blo(u3.y) * sc[2] + sh[2], 0.f);
        acc[3] += fmaxf(bhi(u0.y) * sc[3] + sh[3], 0.f) + fmaxf(bhi(u1.y) * sc[3] + sh[3], 0.f)
                + fmaxf(bhi(u2.y) * sc[3] + sh[3], 0.f) + fmaxf(bhi(u3.y) * sc[3] + sh[3], 0.f);
    }
    for (; i < e; i++) {
        int s = elist[i];
        uint2 u = *(const uint2*)(h1b + (size_t)s * 128 + c0);
        acc[0] += fmaxf(blo(u.x) * sc[0] + sh[0], 0.f);
        acc[1] += fmaxf(bhi(u.x) * sc[1] + sh[1], 0.f);
        acc[2] += fmaxf(blo(u.y) * sc[2] + sh[2], 0.f);
        acc[3] += fmaxf(bhi(u.y) * sc[3] + sh[3], 0.f);
    }
    float inv = (e > b) ? 1.0f / (float)(e - b) : 1.0f;
    uint2 ow;
    ow.x = cvt2(acc[0] * inv, acc[1] * inv);
    ow.y = cvt2(acc[2] * inv, acc[3] * inv);
    *(uint2*)(m2b + (size_t)n * 128 + c0) = ow;
}

// ---------------- SAGE layer 1 (fp32 VALU, K=32+32), writes h1b bf16 + stats ----------------
__global__ __launch_bounds__(256) void k_node_l1(
    const float* __restrict__ meanX, const float* __restrict__ x,
    const float* __restrict__ Wl, const float* __restrict__ Wr,
    const float* __restrict__ bias,
    short* __restrict__ outp, float* __restrict__ ssum, float* __restrict__ ssq)
{
    __shared__ __align__(16) float sWl[32][128];
    __shared__ __align__(16) float sWr[32][128];
    __shared__ __align__(16) float sA[32][36];
    __shared__ __align__(16) float sB[32][36];
    __shared__ float red[2][128], red2[2][128];
    int tid = threadIdx.x;
    int j = tid & 127, rg = tid >> 7;
    int r0 = blockIdx.x * 32;

    for (int f = tid * 4; f < 4096; f += 1024) {
        *(float4*)((float*)sWl + f) = *(const float4*)(Wl + f);
        *(float4*)((float*)sWr + f) = *(const float4*)(Wr + f);
    }
    {
        int r = tid >> 3, c = (tid & 7) * 4;
        *(float4*)(&sA[r][c]) = *(const float4*)(meanX + (size_t)(r0 + r) * 32 + c);
        *(float4*)(&sB[r][c]) = *(const float4*)(x + (size_t)(r0 + r) * 32 + c);
    }
    __syncthreads();

    float acc[16];
    #pragma unroll
    for (int r = 0; r < 16; r++) acc[r] = 0.0f;
    int rb = rg * 16;
    #pragma unroll
    for (int kq = 0; kq < 8; kq++) {
        int k = kq * 4;
        float wl0 = sWl[k][j], wl1 = sWl[k+1][j], wl2 = sWl[k+2][j], wl3 = sWl[k+3][j];
        float wr0 = sWr[k][j], wr1 = sWr[k+1][j], wr2 = sWr[k+2][j], wr3 = sWr[k+3][j];
        #pragma unroll
        for (int r = 0; r < 16; r++) {
            float4 a = *(float4*)(&sA[rb + r][k]);
            float4 b = *(float4*)(&sB[rb + r][k]);
            acc[r] += a.x*wl0 + a.y*wl1 + a.z*wl2 + a.w*wl3
                    + b.x*wr0 + b.y*wr1 + b.z*wr2 + b.w*wr3;
        }
    }
    float bj = bias[j];
    float s1 = 0.0f, s2 = 0.0f;
    #pragma unroll
    for (int r = 0; r < 16; r += 2) {
        float v0 = acc[r] + bj, v1 = acc[r + 1] + bj;
        s1 += v0 + v1; s2 += v0 * v0 + v1 * v1;
        unsigned p = cvt2(v0, v1);
        outp[(size_t)(r0 + rb + r) * 128 + j]     = (short)p;
        outp[(size_t)(r0 + rb + r + 1) * 128 + j] = (short)(p >> 16);
    }
    red[rg][j] = s1; red2[rg][j] = s2;
    __syncthreads();
    if (rg == 0) {
        atomicAdd(&ssum[j], red[0][j] + red[1][j]);
        atomicAdd(&ssq[j],  red2[0][j] + red2[1][j]);
    }
}

// ---------------- SAGE layer 2 via MFMA (bn1 inlined): h2 = [mean | bnrelu(h1)] @ W2c + b2 ----------------
__global__ __launch_bounds__(256) void k_node_l2m(
    const short* __restrict__ m2b, const short* __restrict__ h1b,
    const float* __restrict__ ssum1, const float* __restrict__ ssq1,
    const float* __restrict__ g1, const float* __restrict__ b1g,
    const short* __restrict__ W2cT, const float* __restrict__ bias,
    short* __restrict__ h2b, float* __restrict__ ssum, float* __restrict__ ssq)
{
    __shared__ __align__(16) short sK[32][264];
    __shared__ float sRed[2][128];
    __shared__ float sS[128], sH[128];
    const int tid = threadIdx.x;
    const int wave = tid >> 6, lane = tid & 63, quad = lane >> 4, ln = lane & 15;
    const int waveM = wave >> 1, waveN = wave & 1;
    const int colbase = 64 * waveN, row16 = 16 * waveM;
    if (tid < 128) {
        float m = ssum1[tid] / (float)NN;
        float var = ssq1[tid] / (float)NN - m * m;
        float rs = rsqrtf(var + 1e-5f);
        float s = g1[tid] * rs;
        sS[tid] = s; sH[tid] = b1g[tid] - m * s;
        sRed[0][tid] = 0.f; sRed[1][tid] = 0.f;
    }

    bf16x8 bW[4][8];
    #pragma unroll
    for (int nt = 0; nt < 4; nt++)
        #pragma unroll
        for (int kk = 0; kk < 8; kk++)
            bW[nt][kk] = *(const bf16x8*)(W2cT + (size_t)(colbase + nt * 16 + ln) * 256 + kk * 32 + quad * 8);
    float bc[4];
    #pragma unroll
    for (int nt = 0; nt < 4; nt++) bc[nt] = bias[colbase + nt * 16 + ln];

    float s1[4] = {0,0,0,0}, s2[4] = {0,0,0,0};
    f32x4 zero = {0.f, 0.f, 0.f, 0.f};
    __syncthreads();

    for (int t = blockIdx.x; t < NN / 32; t += gridDim.x) {
        int r0 = t * 32;
        __syncthreads();
        {
            int r = tid >> 3, seg = tid & 7;
            if (seg < 4) {
                const bf16x8* src = (const bf16x8*)(m2b + (size_t)(r0 + r) * 128 + seg * 32);
                bf16x8* dst = (bf16x8*)(&sK[r][seg * 32]);
                dst[0] = src[0]; dst[1] = src[1]; dst[2] = src[2]; dst[3] = src[3];
            } else {
                int c0 = (seg - 4) * 32;
                const uint4* pw = (const uint4*)(h1b + (size_t)(r0 + r) * 128 + c0);
                uint4* dw = (uint4*)(&sK[r][128 + c0]);
                #pragma unroll
                for (int i2 = 0; i2 < 4; i2++) {
                    uint4 u = pw[i2];
                    int cb = c0 + i2 * 8;
                    uint4 ow;
                    ow.x = cvt2(fmaxf(blo(u.x)*sS[cb+0]+sH[cb+0],0.f), fmaxf(bhi(u.x)*sS[cb+1]+sH[cb+1],0.f));
                    ow.y = cvt2(fmaxf(blo(u.y)*sS[cb+2]+sH[cb+2],0.f), fmaxf(bhi(u.y)*sS[cb+3]+sH[cb+3],0.f));
                    ow.z = cvt2(fmaxf(blo(u.z)*sS[cb+4]+sH[cb+4],0.f), fmaxf(bhi(u.z)*sS[cb+5]+sH[cb+5],0.f));
                    ow.w = cvt2(fmaxf(blo(u.w)*sS[cb+6]+sH[cb+6],0.f), fmaxf(bhi(u.w)*sS[cb+7]+sH[cb+7],0.f));
                    dw[i2] = ow;
                }
            }
        }
        __syncthreads();
        f32x4 acc[4] = {zero, zero, zero, zero};
        #pragma unroll
        for (int kk = 0; kk < 8; kk++) {
            bf16x8 a = *(const bf16x8*)(&sK[row16 + ln][kk * 32 + quad * 8]);
            #pragma unroll
            for (int nt = 0; nt < 4; nt++)
                acc[nt] = __builtin_amdgcn_mfma_f32_16x16x32_bf16(a, bW[nt][kk], acc[nt], 0, 0, 0);
        }
        #pragma unroll
        for (int nt = 0; nt < 4; nt++) {
            int col = colbase + nt * 16 + ln;
            float v0 = acc[nt][0] + bc[nt], v1 = acc[nt][1] + bc[nt];
            float v2 = acc[nt][2] + bc[nt], v3 = acc[nt][3] + bc[nt];
            s1[nt] += (v0 + v1) + (v2 + v3);
            s2[nt] += (v0*v0 + v1*v1) + (v2*v2 + v3*v3);
            unsigned p01 = cvt2(v0, v1), p23 = cvt2(v2, v3);
            h2b[(size_t)(r0 + row16 + quad * 4 + 0) * 128 + col] = (short)p01;
            h2b[(size_t)(r0 + row16 + quad * 4 + 1) * 128 + col] = (short)(p01 >> 16);
            h2b[(size_t)(r0 + row16 + quad * 4 + 2) * 128 + col] = (short)p23;
            h2b[(size_t)(r0 + row16 + quad * 4 + 3) * 128 + col] = (short)(p23 >> 16);
        }
    }
    #pragma unroll
    for (int nt = 0; nt < 4; nt++) {
        float a1 = s1[nt], a2 = s2[nt];
        a1 += __shfl_down(a1, 32); a1 += __shfl_down(a1, 16);
        a2 += __shfl_down(a2, 32); a2 += __shfl_down(a2, 16);
        if (quad == 0) {
            atomicAdd(&sRed[0][colbase + nt * 16 + ln], a1);
            atomicAdd(&sRed[1][colbase + nt * 16 + ln], a2);
        }
    }
    __syncthreads();
    if (tid < 128) {
        atomicAdd(&ssum[tid], sRed[0][tid]);
        atomicAdd(&ssq[tid],  sRed[1][tid]);
    }
}

// ---------------- node projection (bn2 inlined): both hs and hd in one launch ----------------
__global__ __launch_bounds__(256) void k_proj_mfma(
    const short* __restrict__ h2b,
    const float* __restrict__ ssum2, const float* __restrict__ ssq2,
    const float* __restrict__ g2, const float* __restrict__ b2g,
    const short* __restrict__ WT0, const short* __restrict__ WT1,
    short* __restrict__ C0, short* __restrict__ C1)
{
    __shared__ __align__(16) short sA[32][136];
    __shared__ float sS[128], sH[128];
    const int tid = threadIdx.x;
    const int wave = tid >> 6, lane = tid & 63, quad = lane >> 4, ln = lane & 15;
    const int waveM = wave >> 1, waveN = wave & 1;
    const int colbase = 64 * waveN, row16 = 16 * waveM;
    const int half = (blockIdx.x >= 512) ? 1 : 0;
    const short* WT = half ? WT1 : WT0;
    short* C = half ? C1 : C0;
    const int b0 = blockIdx.x - half * 512;
    if (tid < 128) {
        float m = ssum2[tid] / (float)NN;
        float var = ssq2[tid] / (float)NN - m * m;
        float rs = rsqrtf(var + 1e-5f);
        float s = g2[tid] * rs;
        sS[tid] = s; sH[tid] = b2g[tid] - m * s;
    }
    bf16x8 bW[4][4];
    #pragma unroll
    for (int nt = 0; nt < 4; nt++)
        #pragma unroll
        for (int kk = 0; kk < 4; kk++)
            bW[nt][kk] = *(const bf16x8*)(WT + (colbase + nt * 16 + ln) * 128 + kk * 32 + quad * 8);
    f32x4 zero = {0.f, 0.f, 0.f, 0.f};
    __syncthreads();
    for (int t = b0; t < NN / 32; t += 512) {
        int r0 = t * 32;
        __syncthreads();
        {
            int r = tid >> 3, c0 = (tid & 7) * 16;
            const uint4* pw = (const uint4*)(h2b + (size_t)(r0 + r) * 128 + c0);
            uint4* dw = (uint4*)(&sA[r][c0]);
            #pragma unroll
            for (int i2 = 0; i2 < 2; i2++) {
                uint4 u = pw[i2];
                int cb = c0 + i2 * 8;
                uint4 ow;
                ow.x = cvt2(fmaxf(blo(u.x)*sS[cb+0]+sH[cb+0],0.f), fmaxf(bhi(u.x)*sS[cb+1]+sH[cb+1],0.f));
                ow.y = cvt2(fmaxf(blo(u.y)*sS[cb+2]+sH[cb+2],0.f), fmaxf(bhi(u.y)*sS[cb+3]+sH[cb+3],0.f));
                ow.z = cvt2(fmaxf(blo(u.z)*sS[cb+4]+sH[cb+4],0.f), fmaxf(bhi(u.z)*sS[cb+5]+sH[cb+5],0.f));
                ow.w = cvt2(fmaxf(blo(u.w)*sS[cb+6]+sH[cb+6],0.f), fmaxf(bhi(u.w)*sS[cb+7]+sH[cb+7],0.f));
                dw[i2] = ow;
            }
        }
        __syncthreads();
        f32x4 acc[4] = {zero, zero, zero, zero};
        #pragma unroll
        for (int kk = 0; kk < 4; kk++) {
            bf16x8 a = *(const bf16x8*)(&sA[row16 + ln][kk * 32 + quad * 8]);
            #pragma unroll
            for (int nt = 0; nt < 4; nt++)
                acc[nt] = __builtin_amdgcn_mfma_f32_16x16x32_bf16(a, bW[nt][kk], acc[nt], 0, 0, 0);
        }
        #pragma unroll
        for (int nt = 0; nt < 4; nt++) {
            int col = colbase + nt * 16 + ln;
            unsigned p01 = cvt2(acc[nt][0], acc[nt][1]);
            unsigned p23 = cvt2(acc[nt][2], acc[nt][3]);
            C[(size_t)(r0 + row16 + quad * 4 + 0) * 128 + col] = (short)p01;
            C[(size_t)(r0 + row16 + quad * 4 + 1) * 128 + col] = (short)(p01 >> 16);
            C[(size_t)(r0 + row16 + quad * 4 + 2) * 128 + col] = (short)p23;
            C[(size_t)(r0 + row16 + quad * 4 + 3) * 128 + col] = (short)(p23 >> 16);
        }
    }
}

// ---------------- edge MODE1, 64-edge tiles, 512 threads (8 waves) ----------------
// v = relu(t@W1p + bm1p + hs[es] + hd[et]); bnm stats; store v. Pipelined.
// Staging: 16 threads per edge-row (scol=(tid&15)*8), each thread covers rows srow and srow+32
// -> conflict-free-ish sSum writes (round-6 bank profile) with round-7's halved barrier count.
__global__ __launch_bounds__(512) void k_edge_m1(
    const float* __restrict__ ea,
    const short* __restrict__ WteT, const float* __restrict__ be,
    const short* __restrict__ W1pT, const float* __restrict__ bm1p,
    const short* __restrict__ hs, const short* __restrict__ hd,
    const int* __restrict__ esrc, const int* __restrict__ etgt,
    float* __restrict__ ssum, float* __restrict__ ssq,
    short* __restrict__ vbuf)
{
    __shared__ __align__(16) short sT[64][136];
    __shared__ __align__(16) float sSum[64][132];
    __shared__ float sRed[2][128];

    const int tid = threadIdx.x;
    const int wave = tid >> 6, lane = tid & 63;
    const int quad = lane >> 4, ln = lane & 15;
    const int waveM = wave >> 1, waveN = wave & 1;
    const int colbase = 64 * waveN, row16 = 16 * waveM;

    if (tid < 128) { sRed[0][tid] = 0.f; sRed[1][tid] = 0.f; }

    bf16x8 bWe[4], bW1[4][4];
    float bec[4], bmc[4];
    #pragma unroll
    for (int nt = 0; nt < 4; nt++) {
        bWe[nt] = *(const bf16x8*)(WteT + (colbase + nt * 16 + ln) * 32 + quad * 8);
        #pragma unroll
        for (int kk = 0; kk < 4; kk++)
            bW1[nt][kk] = *(const bf16x8*)(W1pT + (colbase + nt * 16 + ln) * 128 + kk * 32 + quad * 8);
        bec[nt] = be[colbase + nt * 16 + ln];
        bmc[nt] = bm1p[colbase + nt * 16 + ln];
    }

    // staging geometry: 16 threads per edge-row, 8 cols (16 B) each; rows srow and srow+32
    const int srow = tid >> 4;          // 0..31
    const int scol = (tid & 15) * 8;    // 0..120

    float s1[4] = {0,0,0,0}, s2[4] = {0,0,0,0};
    f32x4 zero = {0.f, 0.f, 0.f, 0.f};

    const int G = gridDim.x;
    const int NT = NE / 64;
    bf16x8 gA = {}, gB = {}, gC = {}, gD = {};        // hs/hd for rows srow, srow+32
    int i1sA = 0, i1tA = 0, i1sB = 0, i1tB = 0;       // indices for tile t+G
    float4 fe0 = {0,0,0,0}, fe1 = {0,0,0,0};          // eattr for tile t (quad<2)

    int t = blockIdx.x;
    if (t < NT) {
        const int e0 = t * 64;
        int s0 = esrc[e0 + srow],       d0 = etgt[e0 + srow];
        int s1i = esrc[e0 + srow + 32], d1 = etgt[e0 + srow + 32];
        gA = *(const bf16x8*)(hs + (size_t)s0 * 128 + scol);
        gB = *(const bf16x8*)(hd + (size_t)d0 * 128 + scol);
        gC = *(const bf16x8*)(hs + (size_t)s1i * 128 + scol);
        gD = *(const bf16x8*)(hd + (size_t)d1 * 128 + scol);
        int t1 = t + G;
        if (t1 < NT) {
            i1sA = esrc[t1 * 64 + srow];      i1tA = etgt[t1 * 64 + srow];
            i1sB = esrc[t1 * 64 + srow + 32]; i1tB = etgt[t1 * 64 + srow + 32];
        }
        if (quad < 2) {
            const float* p = ea + (size_t)(e0 + row16 + ln) * 16 + quad * 8;
            fe0 = *(const float4*)p; fe1 = *(const float4*)(p + 4);
        }
    }

    for (; t < NT; t += G) {
        const int e0 = t * 64;

        // ---- t-GEMM from prefetched eattr ----
        bf16x8 aE;
        if (quad < 2) {
            uint4 uw;
            uw.x = cvt2(fe0.x, fe0.y); uw.y = cvt2(fe0.z, fe0.w);
            uw.z = cvt2(fe1.x, fe1.y); uw.w = cvt2(fe1.z, fe1.w);
            aE = *(bf16x8*)&uw;
        } else {
            #pragma unroll
            for (int i = 0; i < 8; i++) aE[i] = 0;
        }
        f32x4 tacc[4];
        #pragma unroll
        for (int nt = 0; nt < 4; nt++)
            tacc[nt] = __builtin_amdgcn_mfma_f32_16x16x32_bf16(aE, bWe[nt], zero, 0, 0, 0);

        __syncthreads();   // prev iteration finished reading sT/sSum

        // ---- write sT (packed cvt) ----
        #pragma unroll
        for (int nt = 0; nt < 4; nt++) {
            int col = colbase + nt * 16 + ln;
            unsigned p01 = cvt2(fmaxf(tacc[nt][0] + bec[nt], 0.f), fmaxf(tacc[nt][1] + bec[nt], 0.f));
            unsigned p23 = cvt2(fmaxf(tacc[nt][2] + bec[nt], 0.f), fmaxf(tacc[nt][3] + bec[nt], 0.f));
            sT[row16 + quad * 4 + 0][col] = (short)p01;
            sT[row16 + quad * 4 + 1][col] = (short)(p01 >> 16);
            sT[row16 + quad * 4 + 2][col] = (short)p23;
            sT[row16 + quad * 4 + 3][col] = (short)(p23 >> 16);
        }
        // ---- write sSum from in-flight gathers (word-wise unpack) ----
        {
            uint4 uA = *(const uint4*)&gA, uB = *(const uint4*)&gB;
            uint4 uC = *(const uint4*)&gC, uD = *(const uint4*)&gD;
            f32x4 a0, a1, b0, b1;
            a0[0] = blo(uA.x) + blo(uB.x); a0[1] = bhi(uA.x) + bhi(uB.x);
            a0[2] = blo(uA.y) + blo(uB.y); a0[3] = bhi(uA.y) + bhi(uB.y);
            a1[0] = blo(uA.z) + blo(uB.z); a1[1] = bhi(uA.z) + bhi(uB.z);
            a1[2] = blo(uA.w) + blo(uB.w); a1[3] = bhi(uA.w) + bhi(uB.w);
            b0[0] = blo(uC.x) + blo(uD.x); b0[1] = bhi(uC.x) + bhi(uD.x);
            b0[2] = blo(uC.y) + blo(uD.y); b0[3] = bhi(uC.y) + bhi(uD.y);
            b1[0] = blo(uC.z) + blo(uD.z); b1[1] = bhi(uC.z) + bhi(uD.z);
            b1[2] = blo(uC.w) + blo(uD.w); b1[3] = bhi(uC.w) + bhi(uD.w);
            *(f32x4*)(&sSum[srow][scol])          = a0;
            *(f32x4*)(&sSum[srow][scol + 4])      = a1;
            *(f32x4*)(&sSum[srow + 32][scol])     = b0;
            *(f32x4*)(&sSum[srow + 32][scol + 4]) = b1;
        }
        // ---- prefetch next tile: gathers (idx resident), idx+2, eattr+1 ----
        {
            int t1 = t + G;
            if (t1 < NT) {
                gA = *(const bf16x8*)(hs + (size_t)i1sA * 128 + scol);
                gB = *(const bf16x8*)(hd + (size_t)i1tA * 128 + scol);
                gC = *(const bf16x8*)(hs + (size_t)i1sB * 128 + scol);
                gD = *(const bf16x8*)(hd + (size_t)i1tB * 128 + scol);
                int t2 = t1 + G;
                if (t2 < NT) {
                    i1sA = esrc[t2 * 64 + srow];      i1tA = etgt[t2 * 64 + srow];
                    i1sB = esrc[t2 * 64 + srow + 32]; i1tB = etgt[t2 * 64 + srow + 32];
                }
                if (quad < 2) {
                    const float* p = ea + (size_t)(t1 * 64 + row16 + ln) * 16 + quad * 8;
                    fe0 = *(const float4*)p; fe1 = *(const float4*)(p + 4);
                }
            }
        }
        __syncthreads();

        // ---- u-GEMM ----
        f32x4 uacc[4] = {zero, zero, zero, zero};
        #pragma unroll
        for (int kk = 0; kk < 4; kk++) {
            bf16x8 aU = *(const bf16x8*)(&sT[row16 + ln][kk * 32 + quad * 8]);
            #pragma unroll
            for (int nt = 0; nt < 4; nt++)
                uacc[nt] = __builtin_amdgcn_mfma_f32_16x16x32_bf16(aU, bW1[nt][kk], uacc[nt], 0, 0, 0);
        }
        // ---- v + stats + store (packed cvt) ----
        #pragma unroll
        for (int nt = 0; nt < 4; nt++) {
            int col = colbase + nt * 16 + ln;
            float v0 = fmaxf(uacc[nt][0] + bmc[nt] + sSum[row16 + quad * 4 + 0][col], 0.f);
            float v1 = fmaxf(uacc[nt][1] + bmc[nt] + sSum[row16 + quad * 4 + 1][col], 0.f);
            float v2 = fmaxf(uacc[nt][2] + bmc[nt] + sSum[row16 + quad * 4 + 2][col], 0.f);
            float v3 = fmaxf(uacc[nt][3] + bmc[nt] + sSum[row16 + quad * 4 + 3][col], 0.f);
            s1[nt] += (v0 + v1) + (v2 + v3);
            s2[nt] += (v0*v0 + v1*v1) + (v2*v2 + v3*v3);
            unsigned p01 = cvt2(v0, v1), p23 = cvt2(v2, v3);
            vbuf[(size_t)(e0 + row16 + quad * 4 + 0) * 128 + col] = (short)p01;
            vbuf[(size_t)(e0 + row16 + quad * 4 + 1) * 128 + col] = (short)(p01 >> 16);
            vbuf[(size_t)(e0 + row16 + quad * 4 + 2) * 128 + col] = (short)p23;
            vbuf[(size_t)(e0 + row16 + quad * 4 + 3) * 128 + col] = (short)(p23 >> 16);
        }
    }

    #pragma unroll
    for (int nt = 0; nt < 4; nt++) {
        float a1 = s1[nt], a2 = s2[nt];
        a1 += __shfl_down(a1, 32); a1 += __shfl_down(a1, 16);
        a2 += __shfl_down(a2, 32); a2 += __shfl_down(a2, 16);
        if (quad == 0) {
            atomicAdd(&sRed[0][colbase + nt * 16 + ln], a1);
            atomicAdd(&sRed[1][colbase + nt * 16 + ln], a2);
        }
    }
    __syncthreads();
    if (tid < 128) {
        atomicAdd(&ssum[tid], sRed[0][tid]);
        atomicAdd(&ssq[tid],  sRed[1][tid]);
    }
}

// ---------------- edge pipeline via MFMA (modes 2 & 3; mode 2 = non-storev fallback) ----------------
template<int MODE, bool STOREV = false>
__global__ __launch_bounds__(256) void k_edge_mfma(
    const float* __restrict__ ea,
    const short* __restrict__ WteT, const float* __restrict__ be,
    const short* __restrict__ W1pT, const float* __restrict__ bm1p,
    const short* __restrict__ hs, const short* __restrict__ hd,
    const int* __restrict__ esrc, const int* __restrict__ etgt,
    const float* __restrict__ Wm2, const float* __restrict__ bm2,
    const float* __restrict__ bnm_g, const float* __restrict__ bnm_b,
    const float* __restrict__ Wm3, const float* __restrict__ bm3,
    float* __restrict__ ssum, float* __restrict__ ssq,
    short* __restrict__ vbuf, float* __restrict__ outp)
{
    __shared__ __align__(16) short sT[32][136];
    __shared__ __align__(16) float sSum[32][132];
    __shared__ float sRed[2][128];
    __shared__ __align__(16) short sW2[64][136];
    __shared__ float sZ[32][69];                    // also scratch for inlined fold (preamble)
    __shared__ float sW3[64];

    const int tid = threadIdx.x;
    const int wave = tid >> 6, lane = tid & 63;
    const int quad = lane >> 4, ln = lane & 15;
    const int waveM = wave >> 1, waveN = wave & 1;
    const int colbase = 64 * waveN, row16 = 16 * waveM;

    if (MODE < 2) {
        if (tid < 128) { sRed[0][tid] = 0.f; sRed[1][tid] = 0.f; }
    }
    float b2c[2] = {0.f, 0.f};
    if (MODE >= 2) {
        // ---- inlined fold of bnm (from stats) into sW2 / b2 ----
        float* sSc   = (float*)sZ;          // 128
        float* sSh   = sSc + 128;           // 128
        float* sPart = sSh + 128;           // 256
        float* sB2   = sPart + 256;         // 64
        if (tid < 128) {
            float m = ssum[tid] / (float)NE;
            float var = ssq[tid] / (float)NE - m * m;
            float rs = rsqrtf(var + 1e-5f);
            float a = bnm_g[tid] * rs;
            sSc[tid] = a; sSh[tid] = bnm_b[tid] - m * a;
        }
        if (tid < 64) sW3[tid] = Wm3[tid];
        __syncthreads();
        {
            int col = tid & 63, kg = tid >> 6;
            float acc = 0.f;
            for (int k = kg * 32; k < kg * 32 + 32; k++) {
                float w = Wm2[k * 64 + col];
                sW2[col][k] = f2b(sSc[k] * w);
                acc += sSh[k] * w;
            }
            sPart[kg * 64 + col] = acc;
        }
        __syncthreads();
        if (tid < 64)
            ((float*)sZ)[512 + tid] = bm2[tid] + sPart[tid] + sPart[64 + tid]
                                    + sPart[128 + tid] + sPart[192 + tid];
        __syncthreads();
        b2c[0] = sB2[32 * waveN + ln];
        b2c[1] = sB2[32 * waveN + 16 + ln];
    }

    bf16x8 bWe[4], bW1[4][4];
    if (MODE <= 2) {
        #pragma unroll
        for (int nt = 0; nt < 4; nt++) {
            bWe[nt] = *(const bf16x8*)(WteT + (colbase + nt * 16 + ln) * 32 + quad * 8);
            if (MODE >= 1) {
                #pragma unroll
                for (int kk = 0; kk < 4; kk++)
                    bW1[nt][kk] = *(const bf16x8*)(W1pT + (colbase + nt * 16 + ln) * 128 + kk * 32 + quad * 8);
            }
        }
    }
    float bec[4], bmc[4];
    #pragma unroll
    for (int nt = 0; nt < 4; nt++) {
        bec[nt] = (MODE <= 2) ? be[colbase + nt * 16 + ln] : 0.f;
        bmc[nt] = (MODE == 1 || MODE == 2) ? bm1p[colbase + nt * 16 + ln] : 0.f;
    }
    float bm3v = (MODE >= 2) ? bm3[0] : 0.f;

    const int srow = tid >> 4;          // 0..15
    const int scol = (tid & 15) * 8;    // 0..120

    float s1[4] = {0,0,0,0}, s2[4] = {0,0,0,0};
    f32x4 zero = {0.f, 0.f, 0.f, 0.f};
    __syncthreads();

    if constexpr (MODE == 3) {
        // ---------------- pipelined MODE 3: vbuf prefetch ----------------
        const int G = gridDim.x;
        const int NT = NE / 32;
        bf16x8 aV0 = {}, aV1 = {}, aV2 = {}, aV3 = {};
        int t = blockIdx.x;
        if (t < NT) {
            const short* p = vbuf + (size_t)(t * 32 + row16 + ln) * 128 + quad * 8;
            aV0 = *(const bf16x8*)(p);
            aV1 = *(const bf16x8*)(p + 32);
            aV2 = *(const bf16x8*)(p + 64);
            aV3 = *(const bf16x8*)(p + 96);
        }
        for (; t < NT; t += G) {
            const int e0 = t * 32;
            f32x4 vacc[2] = {zero, zero};
            #pragma unroll
            for (int n2 = 0; n2 < 2; n2++) {
                bf16x8 bV0 = *(const bf16x8*)(&sW2[32 * waveN + n2 * 16 + ln][0 * 32 + quad * 8]);
                bf16x8 bV1 = *(const bf16x8*)(&sW2[32 * waveN + n2 * 16 + ln][1 * 32 + quad * 8]);
                bf16x8 bV2 = *(const bf16x8*)(&sW2[32 * waveN + n2 * 16 + ln][2 * 32 + quad * 8]);
                bf16x8 bV3 = *(const bf16x8*)(&sW2[32 * waveN + n2 * 16 + ln][3 * 32 + quad * 8]);
                vacc[n2] = __builtin_amdgcn_mfma_f32_16x16x32_bf16(aV0, bV0, vacc[n2], 0, 0, 0);
                vacc[n2] = __builtin_amdgcn_mfma_f32_16x16x32_bf16(aV1, bV1, vacc[n2], 0, 0, 0);
                vacc[n2] = __builtin_amdgcn_mfma_f32_16x16x32_bf16(aV2, bV2, vacc[n2], 0, 0, 0);
                vacc[n2] = __builtin_amdgcn_mfma_f32_16x16x32_bf16(aV3, bV3, vacc[n2], 0, 0, 0);
            }
            {
                int t1 = t + G;
                if (t1 < NT) {
                    const short* p = vbuf + (size_t)(t1 * 32 + row16 + ln) * 128 + quad * 8;
                    aV0 = *(const bf16x8*)(p);
                    aV1 = *(const bf16x8*)(p + 32);
                    aV2 = *(const bf16x8*)(p + 64);
                    aV3 = *(const bf16x8*)(p + 96);
                }
            }
            __syncthreads();
            #pragma unroll
            for (int n2 = 0; n2 < 2; n2++) {
                int col2 = 32 * waveN + n2 * 16 + ln;
                #pragma unroll
                for (int r = 0; r < 4; r++)
                    sZ[row16 + quad * 4 + r][col2] = fmaxf(vacc[n2][r] + b2c[n2], 0.f);
            }
            __syncthreads();
            {
                int row = wave * 8 + (lane >> 3);
                int ks  = (lane & 7) * 8;
                float o = 0.f;
                #pragma unroll
                for (int k2 = 0; k2 < 8; k2++)
                    o += sZ[row][ks + k2] * sW3[ks + k2];
                o += __shfl_xor(o, 1);
                o += __shfl_xor(o, 2);
                o += __shfl_xor(o, 4);
                if ((lane & 7) == 0) outp[e0 + row] = o + bm3v;
            }
        }
    } else if constexpr (MODE == 2) {
    // ---------------- MODE 2 fallback (recompute path) ----------------
    for (int t = blockIdx.x; t < NE / 32; t += gridDim.x) {
        const int e0 = t * 32;

        int isA = esrc[e0 + srow],      itA = etgt[e0 + srow];
        int isB = esrc[e0 + srow + 16], itB = etgt[e0 + srow + 16];

        bf16x8 aE;
        if (quad < 2) {
            const float* p = ea + (size_t)(e0 + row16 + ln) * 16 + quad * 8;
            float4 f0 = *(const float4*)p, f1 = *(const float4*)(p + 4);
            uint4 uw;
            uw.x = cvt2(f0.x, f0.y); uw.y = cvt2(f0.z, f0.w);
            uw.z = cvt2(f1.x, f1.y); uw.w = cvt2(f1.z, f1.w);
            aE = *(bf16x8*)&uw;
        } else {
            #pragma unroll
            for (int i = 0; i < 8; i++) aE[i] = 0;
        }
        f32x4 tacc[4];
        #pragma unroll
        for (int nt = 0; nt < 4; nt++)
            tacc[nt] = __builtin_amdgcn_mfma_f32_16x16x32_bf16(aE, bWe[nt], zero, 0, 0, 0);

        __syncthreads();
        {
            bf16x8 gA = *(const bf16x8*)(hs + (size_t)isA * 128 + scol);
            bf16x8 gB = *(const bf16x8*)(hd + (size_t)itA * 128 + scol);
            bf16x8 gC = *(const bf16x8*)(hs + (size_t)isB * 128 + scol);
            bf16x8 gD = *(const bf16x8*)(hd + (size_t)itB * 128 + scol);
            #pragma unroll
            for (int nt = 0; nt < 4; nt++) {
                int col = colbase + nt * 16 + ln;
                unsigned p01 = cvt2(fmaxf(tacc[nt][0] + bec[nt], 0.f), fmaxf(tacc[nt][1] + bec[nt], 0.f));
                unsigned p23 = cvt2(fmaxf(tacc[nt][2] + bec[nt], 0.f), fmaxf(tacc[nt][3] + bec[nt], 0.f));
                sT[row16 + quad * 4 + 0][col] = (short)p01;
                sT[row16 + quad * 4 + 1][col] = (short)(p01 >> 16);
                sT[row16 + quad * 4 + 2][col] = (short)p23;
                sT[row16 + quad * 4 + 3][col] = (short)(p23 >> 16);
            }
            uint4 uA = *(const uint4*)&gA, uB = *(const uint4*)&gB;
            uint4 uC = *(const uint4*)&gC, uD = *(const uint4*)&gD;
            f32x4 a0, a1, b0, b1;
            a0[0] = blo(uA.x) + blo(uB.x); a0[1] = bhi(uA.x) + bhi(uB.x);
            a0[2] = blo(uA.y) + blo(uB.y); a0[3] = bhi(uA.y) + bhi(uB.y);
            a1[0] = blo(uA.z) + blo(uB.z); a1[1] = bhi(uA.z) + bhi(uB.z);
            a1[2] = blo(uA.w) + blo(uB.w); a1[3] = bhi(uA.w) + bhi(uB.w);
            b0[0] = blo(uC.x) + blo(uD.x); b0[1] = bhi(uC.x) + bhi(uD.x);
            b0[2] = blo(uC.y) + blo(uD.y); b0[3] = bhi(uC.y) + bhi(uD.y);
            b1[0] = blo(uC.z) + blo(uD.z); b1[1] = bhi(uC.z) + bhi(uD.z);
            b1[2] = blo(uC.w) + blo(uD.w); b1[3] = bhi(uC.w) + bhi(uD.w);
            *(f32x4*)(&sSum[srow][scol])          = a0;
            *(f32x4*)(&sSum[srow][scol + 4])      = a1;
            *(f32x4*)(&sSum[srow + 16][scol])     = b0;
            *(f32x4*)(&sSum[srow + 16][scol + 4]) = b1;
        }
        __syncthreads();

        f32x4 uacc[4] = {zero, zero, zero, zero};
        #pragma unroll
        for (int kk = 0; kk < 4; kk++) {
            bf16x8 aU = *(const bf16x8*)(&sT[row16 + ln][kk * 32 + quad * 8]);
            #pragma unroll
            for (int nt = 0; nt < 4; nt++)
                uacc[nt] = __builtin_amdgcn_mfma_f32_16x16x32_bf16(aU, bW1[nt][kk], uacc[nt], 0, 0, 0);
        }

        __syncthreads();
        #pragma unroll
        for (int nt = 0; nt < 4; nt++) {
            int col = colbase + nt * 16 + ln;
            #pragma unroll
            for (int r = 0; r < 4; r++) {
                float v = uacc[nt][r] + bmc[nt] + sSum[row16 + quad * 4 + r][col];
                sT[row16 + quad * 4 + r][col] = f2b(fmaxf(v, 0.f));
            }
        }
        __syncthreads();
        f32x4 vacc[2] = {zero, zero};
        #pragma unroll
        for (int kk = 0; kk < 4; kk++) {
            bf16x8 aV = *(const bf16x8*)(&sT[row16 + ln][kk * 32 + quad * 8]);
            #pragma unroll
            for (int n2 = 0; n2 < 2; n2++) {
                bf16x8 bV = *(const bf16x8*)(&sW2[32 * waveN + n2 * 16 + ln][kk * 32 + quad * 8]);
                vacc[n2] = __builtin_amdgcn_mfma_f32_16x16x32_bf16(aV, bV, vacc[n2], 0, 0, 0);
            }
        }
        #pragma unroll
        for (int n2 = 0; n2 < 2; n2++) {
            int col2 = 32 * waveN + n2 * 16 + ln;
            #pragma unroll
            for (int r = 0; r < 4; r++)
                sZ[row16 + quad * 4 + r][col2] = fmaxf(vacc[n2][r] + b2c[n2], 0.f);
        }
        __syncthreads();
        {
            int row = wave * 8 + (lane >> 3);
            int ks  = (lane & 7) * 8;
            float o = 0.f;
            #pragma unroll
            for (int k2 = 0; k2 < 8; k2++)
                o += sZ[row][ks + k2] * sW3[ks + k2];
            o += __shfl_xor(o, 1);
            o += __shfl_xor(o, 2);
            o += __shfl_xor(o, 4);
            if ((lane & 7) == 0) outp[e0 + row] = o + bm3v;
        }
    }
    }  // end MODE dispatch

    if (MODE < 2) {
        #pragma unroll
        for (int nt = 0; nt < 4; nt++) {
            float a1 = s1[nt], a2 = s2[nt];
            a1 += __shfl_down(a1, 32); a1 += __shfl_down(a1, 16);
            a2 += __shfl_down(a2, 32); a2 += __shfl_down(a2, 16);
            if (quad == 0) {
                atomicAdd(&sRed[0][colbase + nt * 16 + ln], a1);
                atomicAdd(&sRed[1][colbase + nt * 16 + ln], a2);
            }
        }
        __syncthreads();
        if (tid < 128) {
            atomicAdd(&ssum[tid], sRed[0][tid]);
            atomicAdd(&ssq[tid],  sRed[1][tid]);
        }
    }
}

extern "C" void kernel_launch(void* const* d_in, const int* in_sizes, int n_in,
                              void* d_out, int out_size, void* d_ws, size_t ws_size,
                              hipStream_t stream) {
    const float* x     = (const float*)d_in[0];
    const int*   ei    = (const int*)  d_in[1];
    const float* eattr = (const float*)d_in[2];
    const int*   esrc  = (const int*)  d_in[3];
    const int*   etgt  = (const int*)  d_in[4];
    const float* W1l = (const float*)d_in[5];  const float* b1 = (const float*)d_in[6];
    const float* W1r = (const float*)d_in[7];
    const float* W2l = (const float*)d_in[8];  const float* b2 = (const float*)d_in[9];
    const float* W2r = (const float*)d_in[10];
    const float* bn1_g = (const float*)d_in[11]; const float* bn1_b = (const float*)d_in[12];
    const float* bn2_g = (const float*)d_in[13]; const float* bn2_b = (const float*)d_in[14];
    const float* We  = (const float*)d_in[15]; const float* be  = (const float*)d_in[16];
    const float* bne_g = (const float*)d_in[17]; const float* bne_b = (const float*)d_in[18];
    const float* Wm1 = (const float*)d_in[19]; const float* bm1 = (const float*)d_in[20];
    const float* bnm_g = (const float*)d_in[21]; const float* bnm_b = (const float*)d_in[22];
    const float* Wm2 = (const float*)d_in[23]; const float* bm2 = (const float*)d_in[24];
    const float* Wm3 = (const float*)d_in[25]; const float* bm3 = (const float*)d_in[26];
    float* out = (float*)d_out;

    char* base = (char*)d_ws;
    size_t o = 0;
    auto A = [&](size_t bytes) { char* p = base + o; o = (o + bytes + 255) & ~(size_t)255; return p; };
    short* hsb   = (short*)A((size_t)NN * 128 * 2);
    short* hdb   = (short*)A((size_t)NN * 128 * 2);
    int*   deg   = (int*)  A((size_t)NN * 4);
    int*   rowptr= (int*)  A((size_t)(NN + 1) * 4);
    int*   wp    = (int*)  A((size_t)NN * 4);
    int*   elist = (int*)  A((size_t)NE * 4);
    float* st    = (float*)A(1024 * 4);
    int*   bsum  = (int*)  A(SCAN_NB * 4);
    int*   boff  = (int*)  A(SCAN_NB * 4);
    float* sc1   = (float*)A(512); float* sh1 = (float*)A(512);
    float* sc2   = (float*)A(512); float* sh2 = (float*)A(512);
    float* bm1p  = (float*)A(512); float* b2p = (float*)A(256);
    short* WteT  = (short*)A(128 * 32 * 2);
    short* W1pT  = (short*)A(128 * 128 * 2);
    short* WmsT  = (short*)A(128 * 128 * 2);
    short* WmdT  = (short*)A(128 * 128 * 2);
    short* W2pT  = (short*)A(64 * 128 * 2);
    short* W2cT  = (short*)A(128 * 256 * 2);
    size_t chain = o;
    float* meanX = (float*)A((size_t)NN * 32 * 4);
    short* h1b   = (short*)A((size_t)NN * 128 * 2);
    short* m2b   = (short*)A((size_t)NN * 128 * 2);
    short* h2b   = (short*)A((size_t)NN * 128 * 2);
    int*   stmp  = (int*)meanX;                         // scan tmp aliases meanX (dead until gagg1)
    short* vbuf  = (short*)(base + chain);              // aliases meanX..h2b (all dead by then)
    bool storev = ws_size >= chain + (size_t)NE * 128 * 2;
    (void)W2pT; (void)b2p; (void)sc1; (void)sh1; (void)sc2; (void)sh2;

    hipMemsetAsync(deg, 0, (size_t)NN * 4, stream);
    hipMemsetAsync(st, 0, 1024 * 4, stream);

    // weight prep + degree histogram (fused), then 3-phase scan
    k_prep_hist<<<5 + (NE + 255) / 256, 256, 0, stream>>>(We, Wm1, W2l, W2r,
        WteT, WmsT, WmdT, W2cT, ei, deg);
    k_scan_a<<<SCAN_NB, 1024, 0, stream>>>(deg, stmp, bsum);
    k_scan_b<<<1, 64, 0, stream>>>(bsum, boff, rowptr);
    k_scan_c<<<SCAN_NB, 1024, 0, stream>>>(stmp, boff, rowptr, wp);

    // CSR scatter + edge bne stats (fused, independent work overlapped)
    k_scat_e0<<<SCAT_NB + 2048, 256, 0, stream>>>(ei, wp, elist,
        eattr, WteT, be, st + 512, st + 640);

    // ---- layer 1: gather-mean + fold_e (fused) ----
    k_gagg1f<<<NN / 8 + 1, 256, 0, stream>>>(x, rowptr, elist, meanX,
        st + 512, st + 640, bne_g, bne_b, Wm1, bm1, W1pT, bm1p);
    k_node_l1<<<NN / 32, 256, 0, stream>>>(meanX, x, W1l, W1r, b1, h1b, st + 0, st + 128);

    // ---- layer 2 (bn1 inlined into consumers) ----
    k_gagg2<<<NN / 8, 256, 0, stream>>>(h1b, rowptr, elist, st + 0, st + 128, bn1_g, bn1_b, m2b);
    k_node_l2m<<<512, 256, 0, stream>>>(m2b, h1b, st + 0, st + 128, bn1_g, bn1_b,
        W2cT, b2, h2b, st + 256, st + 384);

    // ---- node projections (bn2 inlined; both in one launch) ----
    k_proj_mfma<<<1024, 256, 0, stream>>>(h2b, st + 256, st + 384, bn2_g, bn2_b,
        WmsT, WmdT, hsb, hdb);

    // ---- edge main ----
    if (storev)
        // 512 blocks x 512 thr = 2 blocks/CU (LDS 52.2KB, VGPR<=128), 64-edge tiles
        k_edge_m1<<<512, 512, 0, stream>>>(eattr, WteT, be, W1pT, bm1p, hsb, hdb,
            esrc, etgt, st + 768, st + 896, vbuf);
    else
        k_edge_mfma<2><<<1024, 256, 0, stream>>>(eattr, WteT, be, W1pT, bm1p, hsb, hdb,
            esrc, etgt, Wm2, bm2, bnm_g, bnm_b, Wm3, bm3, st + 768, st + 896, nullptr, out);

    // ---- edge final (fold of bnm inlined in preamble; 1536 = 6 blocks/CU LDS-bound) ----
    if (storev)
        k_edge_mfma<3><<<1536, 256, 0, stream>>>(eattr, WteT, be, W1pT, bm1p, hsb, hdb,
            esrc, etgt, Wm2, bm2, bnm_g, bnm_b, Wm3, bm3, st + 768, st + 896, vbuf, out);
}